// Round 8
// baseline (708.923 us; speedup 1.0000x reference)
//
#include <hip/hip_runtime.h>
#include <hip/hip_fp16.h>

// ---------------------------------------------------------------------------
// GCN 3-layer forward:  (GCNConv -> BN) x2 -> GCNConv
// N=100000, E=1600000, IN=H=128, OUT=64
// Round 7: (1) MFMA f16 GEMM (BN fused, dis-prescaled chunk-major f16 out)
//          (2) per-node src-sorted edge lists via in-LDS bitonic sort
//              -> coherent src-space sweep during gather (L2-resident band)
// ---------------------------------------------------------------------------

constexpr int BSH = 7;            // 128 nodes per bucket
constexpr int NXCD = 8;

typedef _Float16 half8 __attribute__((ext_vector_type(8)));
typedef float f32x4 __attribute__((ext_vector_type(4)));

static __device__ inline ushort f2h(float f) {
    union { __half h; ushort u; } cv;
    cv.h = __float2half_rn(f);
    return cv.u;
}
static __device__ inline float2 h2f2(unsigned int u) {
    union { unsigned int u; __half2 h; } cv;
    cv.u = u;
    return __half22float2(cv.h);
}

#define ACC8(base, v) do { float2 _f; \
    _f = h2f2((v).x); acc[(base)+0] += _f.x; acc[(base)+1] += _f.y; \
    _f = h2f2((v).y); acc[(base)+2] += _f.x; acc[(base)+3] += _f.y; \
    _f = h2f2((v).z); acc[(base)+4] += _f.x; acc[(base)+5] += _f.y; \
    _f = h2f2((v).w); acc[(base)+6] += _f.x; acc[(base)+7] += _f.y; \
} while (0)

// ---- phase A: per-xcd bucket histogram + per-node degree ------------------
__global__ __launch_bounds__(256) void count_k(const int* __restrict__ dst,
                                               int* __restrict__ hist,
                                               int* __restrict__ deg,
                                               int E, int EPB, int nbuk) {
    __shared__ int lh[1024];
    for (int i = threadIdx.x; i < nbuk; i += 256) lh[i] = 0;
    __syncthreads();
    const int e0 = blockIdx.x * EPB;
    const int e1 = min(e0 + EPB, E);
    for (int e = e0 + threadIdx.x; e < e1; e += 256) {
        int d = dst[e];
        atomicAdd(&lh[d >> BSH], 1);
        atomicAdd(&deg[d], 1);
    }
    __syncthreads();
    const int xcd = blockIdx.x & (NXCD - 1);
    for (int i = threadIdx.x; i < nbuk; i += 256) {
        int v = lh[i];
        if (v) atomicAdd(&hist[xcd * nbuk + i], v);
    }
}

__global__ void deg_to_dis_k(const int* __restrict__ deg, float* __restrict__ dis, int n) {
    int i = blockIdx.x * blockDim.x + threadIdx.x;
    if (i < n) dis[i] = rsqrtf((float)deg[i] + 1.0f);   // +1 self loop
}

// ---- phase B: scan hist (key order: bucket-major, xcd-minor) --------------
__global__ __launch_bounds__(256) void scan_hist_k(const int* __restrict__ hist,
                                                   int* __restrict__ cur,
                                                   int* __restrict__ bstart,
                                                   int* __restrict__ row_ptr,
                                                   int nbuk, int n, int E) {
    const int NT = nbuk * NXCD;          // <= 8192 assumed
    const int C = (NT + 255) / 256;      // <= 32
    int vals[32];
    const int tid = threadIdx.x;
    int sum = 0;
#pragma unroll
    for (int k = 0; k < 32; ++k) {
        if (k >= C) break;
        int key = tid * C + k;
        int v = 0;
        if (key < NT) {
            int b = key >> 3, x = key & 7;
            v = hist[x * nbuk + b];
        }
        vals[k] = v;
        sum += v;
    }
    __shared__ int part[256];
    part[tid] = sum;
    __syncthreads();
    for (int off = 1; off < 256; off <<= 1) {
        int t = 0;
        if (tid >= off) t = part[tid - off];
        __syncthreads();
        part[tid] += t;
        __syncthreads();
    }
    int run = (tid == 0) ? 0 : part[tid - 1];
#pragma unroll
    for (int k = 0; k < 32; ++k) {
        if (k >= C) break;
        int key = tid * C + k;
        if (key < NT) {
            int b = key >> 3, x = key & 7;
            cur[x * nbuk + b] = run;
            if (x == 0) bstart[b] = run;
        }
        run += vals[k];
    }
    if (tid == 0) { bstart[nbuk] = E; row_ptr[n] = E; }
}

// ---- phase C: scatter packed edges into (bucket, xcd) segments ------------
__global__ __launch_bounds__(256) void scatter_bucket_k(const int* __restrict__ src,
                                                        const int* __restrict__ dst,
                                                        int* __restrict__ cur,
                                                        unsigned int* __restrict__ ebuf,
                                                        int E, int EPB, int nbuk) {
    const int e0 = blockIdx.x * EPB;
    const int e1 = min(e0 + EPB, E);
    const int xcd = blockIdx.x & (NXCD - 1);
    for (int e = e0 + threadIdx.x; e < e1; e += 256) {
        int d = dst[e];
        int s = src[e];
        int b = d >> BSH;
        int pos = atomicAdd(&cur[xcd * nbuk + b], 1);
        ebuf[pos] = ((unsigned int)s << BSH) | (unsigned int)(d & 127);
    }
}

// ---- phase D: per-bucket sort -> per-node esrc (src-ascending) + row_ptr --
// Bitonic sort of keys (dstLow<<17)|src groups edges by node with src
// ascending inside each list -> the gather sweeps src-space coherently.
__global__ __launch_bounds__(256) void bucket_sort_k(const unsigned int* __restrict__ ebuf,
                                                     const int* __restrict__ bstart,
                                                     int* __restrict__ row_ptr,
                                                     int* __restrict__ esrc, int n) {
    const int b = blockIdx.x;
    const int beg = bstart[b];
    const int end = bstart[b + 1];
    const int len = end - beg;
    const int tid = threadIdx.x;
    __shared__ int cnt[128], off[128];
    __shared__ unsigned int keys[4096];

    // histogram by dstLow -> row_ptr (independent of sort)
    if (tid < 128) cnt[tid] = 0;
    __syncthreads();
    for (int i = beg + tid; i < end; i += 256)
        atomicAdd(&cnt[ebuf[i] & 127], 1);
    __syncthreads();
    if (tid < 128) off[tid] = cnt[tid];
    __syncthreads();
    for (int d = 1; d < 128; d <<= 1) {
        int t = 0;
        if (tid < 128 && tid >= d) t = off[tid - d];
        __syncthreads();
        if (tid < 128) off[tid] += t;
        __syncthreads();
    }
    if (tid < 128) {
        int ex = off[tid] - cnt[tid];                   // exclusive
        int node = (b << BSH) + tid;
        if (node < n) row_ptr[node] = beg + ex;
        cnt[tid] = ex;                                  // cursor for fallback
    }
    __syncthreads();

    if (len <= 4096) {
        int P = 256;
        while (P < len) P <<= 1;
        for (int i = tid; i < P; i += 256) {
            if (i < len) {
                unsigned int p = ebuf[beg + i];
                keys[i] = ((p & 127u) << 17) | (p >> BSH);
            } else {
                keys[i] = 0xFFFFFFFFu;
            }
        }
        __syncthreads();
        for (int k = 2; k <= P; k <<= 1) {
            for (int j = k >> 1; j > 0; j >>= 1) {
                for (int i = tid; i < (P >> 1); i += 256) {
                    int x = ((i & ~(j - 1)) << 1) | (i & (j - 1));
                    int y = x | j;
                    unsigned int a = keys[x], c = keys[y];
                    bool asc = (x & k) == 0;
                    if ((a > c) == asc) { keys[x] = c; keys[y] = a; }
                }
                __syncthreads();
            }
        }
        for (int i = tid; i < len; i += 256)
            esrc[beg + i] = (int)(keys[i] & 0x1FFFFu);
    } else {
        // fallback: unsorted counting scatter
        for (int i = beg + tid; i < end; i += 256) {
            unsigned int p = ebuf[i];
            int l = (int)(p & 127u);
            int pos = beg + atomicAdd(&cnt[l], 1);
            esrc[pos] = (int)(p >> BSH);
        }
    }
}

// ------- MFMA GEMM: Hs = f16( (BN(X) @ W) * dis ), chunk-major out --------
// Block: 256 thr = 4 waves, 64 rows. Wave w computes rows [w*16, w*16+16)
// x all OUTD cols via mfma_f32_16x16x32_f16, K = 128 in 4 steps.
// Hs layout: [NCHUNK][N][32 f16], chunk c holds columns [32c, 32c+32).
template <int OUTD, bool BNIN>
__global__ __launch_bounds__(256) void gemm_mfma_k(const float* __restrict__ X,
                                                   const float* __restrict__ W,
                                                   const float* __restrict__ scale,
                                                   const float* __restrict__ shift,
                                                   const float* __restrict__ dis,
                                                   ushort* __restrict__ Hs, int nn) {
    constexpr int K = 128;
    constexpr int LDA = K + 8;           // f16 pad: 2-way-free banking
    constexpr int NCT = OUTD / 16;       // col tiles: 8 or 4

    __shared__ __align__(16) _Float16 xs[64 * LDA];
    __shared__ __align__(16) _Float16 wt[OUTD * LDA];   // transposed W: [n][k]

    const int tx = threadIdx.x;
    const int row0 = blockIdx.x * 64;

    // stage W^T (K x OUTD f32 -> [OUTD][K] f16)
    {
        const float4* W4 = (const float4*)W;
        constexpr int tot = K * OUTD / 4;
        for (int idx = tx; idx < tot; idx += 256) {
            int k = idx / (OUTD / 4);
            int nq = idx - k * (OUTD / 4);
            float4 w4 = W4[idx];
            wt[(nq * 4 + 0) * LDA + k] = (_Float16)w4.x;
            wt[(nq * 4 + 1) * LDA + k] = (_Float16)w4.y;
            wt[(nq * 4 + 2) * LDA + k] = (_Float16)w4.z;
            wt[(nq * 4 + 3) * LDA + k] = (_Float16)w4.w;
        }
    }
    // stage X tile (64 x K), BN fused, f16
    {
        const float4* X4 = (const float4*)X;
        constexpr int tot = 64 * K / 4;     // 2048
        for (int idx = tx; idx < tot; idx += 256) {
            int r = idx >> 5;
            int kq = idx & 31;
            int gr = row0 + r;
            float4 v = make_float4(0.f, 0.f, 0.f, 0.f);
            if (gr < nn) {
                v = X4[(size_t)gr * 32 + kq];
                if (BNIN) {
                    float4 sc = ((const float4*)scale)[kq];
                    float4 sh = ((const float4*)shift)[kq];
                    v.x = v.x * sc.x + sh.x;
                    v.y = v.y * sc.y + sh.y;
                    v.z = v.z * sc.z + sh.z;
                    v.w = v.w * sc.w + sh.w;
                }
            }
            ushort4 pk;
            pk.x = f2h(v.x); pk.y = f2h(v.y); pk.z = f2h(v.z); pk.w = f2h(v.w);
            *(ushort4*)&xs[r * LDA + kq * 4] = pk;
        }
    }
    __syncthreads();

    const int wave = tx >> 6;
    const int lane = tx & 63;
    const int l15 = lane & 15;
    const int kg = lane >> 4;            // 0..3

    f32x4 acc[NCT];
#pragma unroll
    for (int ct = 0; ct < NCT; ++ct) acc[ct] = (f32x4){0.f, 0.f, 0.f, 0.f};

    // A-frag row = wave*16 + l15 ; k = kk*32 + kg*8 + [0..8)
#pragma unroll
    for (int kk = 0; kk < 4; ++kk) {
        half8 a = *(const half8*)&xs[(wave * 16 + l15) * LDA + kk * 32 + kg * 8];
#pragma unroll
        for (int ct = 0; ct < NCT; ++ct) {
            half8 bfr = *(const half8*)&wt[(ct * 16 + l15) * LDA + kk * 32 + kg * 8];
            acc[ct] = __builtin_amdgcn_mfma_f32_16x16x32_f16(a, bfr, acc[ct], 0, 0, 0);
        }
    }

    // D: col = lane&15 (within ct), row = kg*4 + reg (within wave tile)
    const int mbase = row0 + wave * 16 + kg * 4;
    float dm[4];
#pragma unroll
    for (int reg = 0; reg < 4; ++reg) {
        int m = mbase + reg;
        dm[reg] = (m < nn) ? dis[m] : 0.f;
    }
#pragma unroll
    for (int ct = 0; ct < NCT; ++ct) {
        int ncol = ct * 16 + l15;
        size_t cb = (size_t)(ncol >> 5) * nn * 32 + (ncol & 31);
#pragma unroll
        for (int reg = 0; reg < 4; ++reg) {
            int m = mbase + reg;
            if (m < nn) Hs[cb + (size_t)m * 32] = f2h(acc[ct][reg] * dm[reg]);
        }
    }
}

// ---------------- chunked gather aggregation (+ fused BN stats) ------------
// Per chunk c (32 cols): O[i][32c..32c+32) = dis[i]*(Hs_c[i] + sum Hs_c[src]) + b
// 2 lanes per 64B row; unroll-4; per-node lists are src-ascending -> sweep.
template <int OUTD, bool STATS>
__global__ __launch_bounds__(256) void gather_k(const ushort* __restrict__ Hs,
                                                const float* __restrict__ dis,
                                                const float* __restrict__ b,
                                                const int* __restrict__ row_ptr,
                                                const int* __restrict__ esrc,
                                                float* __restrict__ O,
                                                float* __restrict__ sums,
                                                float* __restrict__ sumsq, int n) {
    constexpr int NCHUNK = OUTD / 32;   // 4 or 2

    __shared__ float s_sum[32];
    __shared__ float s_sq[32];
    if (STATS) {
        if (threadIdx.x < 32) { s_sum[threadIdx.x] = 0.f; s_sq[threadIdx.x] = 0.f; }
        __syncthreads();
    }

    const int chunk = blockIdx.x & (NCHUNK - 1);
    const int nblk  = blockIdx.x / NCHUNK;
    const int g     = threadIdx.x >> 1;     // node within block: 0..127
    const int lane  = threadIdx.x & 1;      // which half of the 64B row
    const int node  = nblk * 128 + g;

    float acc[16];
#pragma unroll
    for (int c = 0; c < 16; ++c) acc[c] = 0.f;
    float o[16];
#pragma unroll
    for (int c = 0; c < 16; ++c) o[c] = 0.f;

    if (node < n) {
        const uint4* Hc = (const uint4*)Hs + (size_t)chunk * n * 4;  // 4 uint4/node

        {   // self row (dis pre-folded into Hs)
            uint4 v0 = Hc[(size_t)node * 4 + lane];
            uint4 v1 = Hc[(size_t)node * 4 + lane + 2];
            ACC8(0, v0);
            ACC8(8, v1);
        }
        const int beg = row_ptr[node];
        const int end = row_ptr[node + 1];
        int j = beg;
        const int end4 = beg + ((end - beg) & ~3);
        for (; j < end4; j += 4) {
            int s0 = esrc[j + 0];
            int s1 = esrc[j + 1];
            int s2 = esrc[j + 2];
            int s3 = esrc[j + 3];
            uint4 a0 = Hc[(size_t)s0 * 4 + lane];
            uint4 a1 = Hc[(size_t)s1 * 4 + lane];
            uint4 a2 = Hc[(size_t)s2 * 4 + lane];
            uint4 a3 = Hc[(size_t)s3 * 4 + lane];
            uint4 c0 = Hc[(size_t)s0 * 4 + lane + 2];
            uint4 c1 = Hc[(size_t)s1 * 4 + lane + 2];
            uint4 c2 = Hc[(size_t)s2 * 4 + lane + 2];
            uint4 c3 = Hc[(size_t)s3 * 4 + lane + 2];
            ACC8(0, a0); ACC8(8, c0);
            ACC8(0, a1); ACC8(8, c1);
            ACC8(0, a2); ACC8(8, c2);
            ACC8(0, a3); ACC8(8, c3);
        }
        for (; j < end; ++j) {
            int s = esrc[j];
            uint4 a = Hc[(size_t)s * 4 + lane];
            uint4 c = Hc[(size_t)s * 4 + lane + 2];
            ACC8(0, a);
            ACC8(8, c);
        }

        float dd = dis[node];
        const float4* B4 = (const float4*)b + chunk * 8 + lane * 2;
        float4 b0 = B4[0];
        float4 b1 = B4[1];
        float4 b2 = B4[4];
        float4 b3 = B4[5];
        o[0]  = acc[0]  * dd + b0.x;
        o[1]  = acc[1]  * dd + b0.y;
        o[2]  = acc[2]  * dd + b0.z;
        o[3]  = acc[3]  * dd + b0.w;
        o[4]  = acc[4]  * dd + b1.x;
        o[5]  = acc[5]  * dd + b1.y;
        o[6]  = acc[6]  * dd + b1.z;
        o[7]  = acc[7]  * dd + b1.w;
        o[8]  = acc[8]  * dd + b2.x;
        o[9]  = acc[9]  * dd + b2.y;
        o[10] = acc[10] * dd + b2.z;
        o[11] = acc[11] * dd + b2.w;
        o[12] = acc[12] * dd + b3.x;
        o[13] = acc[13] * dd + b3.y;
        o[14] = acc[14] * dd + b3.z;
        o[15] = acc[15] * dd + b3.w;

        float4* O4 = (float4*)O + (size_t)node * (OUTD / 4) + chunk * 8 + lane * 2;
        O4[0] = make_float4(o[0], o[1], o[2], o[3]);
        O4[1] = make_float4(o[4], o[5], o[6], o[7]);
        O4[4] = make_float4(o[8], o[9], o[10], o[11]);
        O4[5] = make_float4(o[12], o[13], o[14], o[15]);
    }

    if (STATS) {
        // lanes of equal parity (lane&1) hold the same 16 columns for 32 nodes
        float sv[16], qv[16];
#pragma unroll
        for (int c = 0; c < 16; ++c) { sv[c] = o[c]; qv[c] = o[c] * o[c]; }
#pragma unroll
        for (int c = 0; c < 16; ++c) {
#pragma unroll
            for (int m = 2; m <= 32; m <<= 1) {
                sv[c] += __shfl_xor(sv[c], m);
                qv[c] += __shfl_xor(qv[c], m);
            }
        }
        if ((threadIdx.x & 63) < 2) {
            // lane 0: cols 0-7 and 16-23 of chunk; lane 1: cols 8-15 and 24-31
            int c0 = lane * 8;
            int c1 = 16 + lane * 8;
#pragma unroll
            for (int c = 0; c < 8; ++c) {
                atomicAdd(&s_sum[c0 + c], sv[c]);
                atomicAdd(&s_sq[c0 + c], qv[c]);
                atomicAdd(&s_sum[c1 + c], sv[8 + c]);
                atomicAdd(&s_sq[c1 + c], qv[8 + c]);
            }
        }
        __syncthreads();
        if (threadIdx.x < 32) {
            atomicAdd(&sums[chunk * 32 + threadIdx.x], s_sum[threadIdx.x]);
            atomicAdd(&sumsq[chunk * 32 + threadIdx.x], s_sq[threadIdx.x]);
        }
    }
}

// ---------------- BN finalize: scale/shift from sums ----------------------
__global__ void bn_finalize_k(const float* __restrict__ sums, const float* __restrict__ sumsq,
                              const float* __restrict__ g, const float* __restrict__ be,
                              float* __restrict__ scale, float* __restrict__ shift, int n) {
    int c = threadIdx.x;  // 128 threads
    float inv_n = 1.0f / (float)n;
    float m = sums[c] * inv_n;
    float v = sumsq[c] * inv_n - m * m;
    float sc = rsqrtf(v + 1e-5f) * g[c];
    scale[c] = sc;
    shift[c] = be[c] - m * sc;
}

// ---------------------------------------------------------------------------
extern "C" void kernel_launch(void* const* d_in, const int* in_sizes, int n_in,
                              void* d_out, int out_size, void* d_ws, size_t ws_size,
                              hipStream_t stream) {
    const float* x   = (const float*)d_in[0];
    const int*   ei  = (const int*)d_in[1];
    const float* W1  = (const float*)d_in[2];
    const float* b1  = (const float*)d_in[3];
    const float* g1  = (const float*)d_in[4];
    const float* be1 = (const float*)d_in[5];
    const float* W2  = (const float*)d_in[6];
    const float* b2  = (const float*)d_in[7];
    const float* g2  = (const float*)d_in[8];
    const float* be2 = (const float*)d_in[9];
    const float* W3  = (const float*)d_in[10];
    const float* b3  = (const float*)d_in[11];
    float* out = (float*)d_out;

    const int N = in_sizes[0] / 128;
    const int E = in_sizes[1] / 2;
    const int* src = ei;
    const int* dst = ei + E;
    const int NBUK = (N + 127) >> BSH;

    // ---- workspace layout ----
    float* wsp   = (float*)d_ws;
    float* dis   = wsp;                               // N f32
    float* stats = wsp + N;                           // 512 f32
    int*   hist   = (int*)(stats + 512);              // NBUK*8
    int*   cur    = hist + NBUK * NXCD;               // NBUK*8
    int*   bstart = cur + NBUK * NXCD;                // NBUK+1
    int*   row_ptr = bstart + NBUK + 1 + 63;          // N+1
    float* bufA  = (float*)(row_ptr + N + 1 + 63);    // N*128 f32 region (Hs f16)
    float* bufB  = bufA + (size_t)N * 128;            // N*128 f32 (agg out)
    unsigned int* ebuf = (unsigned int*)(bufB + (size_t)N * 128);  // E u32
    int*   esrc  = (int*)(ebuf + E);                  // E int

    ushort* Hs = (ushort*)bufA;                       // [NCHUNK][N][32] f16
    int* deg = (int*)bufA;                            // N ints (pre-GEMM only)

    float* sums  = stats;
    float* sumsq = stats + 128;
    float* scale = stats + 256;
    float* shift = stats + 384;

    const int BS = 256;
    dim3 blk(BS);
    const int NB = (N + 255) / 256;
    const int SGRID = 512;                 // count/scatter blocks (multiple of 8)
    const int EPB = (E + SGRID - 1) / SGRID;

    // ---- bucket-sorted CSR build (src-ascending per node) ----
    hipMemsetAsync(deg, 0, (size_t)N * 4, stream);
    hipMemsetAsync(hist, 0, (size_t)NBUK * NXCD * 4, stream);
    count_k<<<dim3(SGRID), blk, 0, stream>>>(dst, hist, deg, E, EPB, NBUK);
    deg_to_dis_k<<<dim3(NB), blk, 0, stream>>>(deg, dis, N);
    scan_hist_k<<<dim3(1), blk, 0, stream>>>(hist, cur, bstart, row_ptr, NBUK, N, E);
    scatter_bucket_k<<<dim3(SGRID), blk, 0, stream>>>(src, dst, cur, ebuf, E, EPB, NBUK);
    bucket_sort_k<<<dim3(NBUK), blk, 0, stream>>>(ebuf, bstart, row_ptr, esrc, N);

    const int gemm_grid = (N + 63) / 64;
    const int NBg = (N + 127) / 128;    // gather node-blocks (128 nodes/block)

    // ---- layer 1 ----
    gemm_mfma_k<128, false><<<dim3(gemm_grid), blk, 0, stream>>>(x, W1, nullptr, nullptr,
                                                                 dis, Hs, N);
    hipMemsetAsync(stats, 0, 256 * 4, stream);
    gather_k<128, true><<<dim3(NBg * 4), blk, 0, stream>>>(Hs, dis, b1, row_ptr, esrc,
                                                           bufB, sums, sumsq, N);
    bn_finalize_k<<<dim3(1), dim3(128), 0, stream>>>(sums, sumsq, g1, be1, scale, shift, N);

    // ---- layer 2 (BN applied inside GEMM staging) ----
    gemm_mfma_k<128, true><<<dim3(gemm_grid), blk, 0, stream>>>(bufB, W2, scale, shift,
                                                                dis, Hs, N);
    hipMemsetAsync(stats, 0, 256 * 4, stream);
    gather_k<128, true><<<dim3(NBg * 4), blk, 0, stream>>>(Hs, dis, b2, row_ptr, esrc,
                                                           bufB, sums, sumsq, N);
    bn_finalize_k<<<dim3(1), dim3(128), 0, stream>>>(sums, sumsq, g2, be2, scale, shift, N);

    // ---- layer 3 (OUT = 64, straight to d_out) ----
    gemm_mfma_k<64, true><<<dim3(gemm_grid), blk, 0, stream>>>(bufB, W3, scale, shift,
                                                               dis, Hs, N);
    gather_k<64, false><<<dim3(NBg * 2), blk, 0, stream>>>(Hs, dis, b3, row_ptr, esrc,
                                                           out, nullptr, nullptr, N);
}

// Round 9
// 595.913 us; speedup vs baseline: 1.1896x; 1.1896x over previous
//
#include <hip/hip_runtime.h>
#include <hip/hip_fp16.h>

// ---------------------------------------------------------------------------
// GCN 3-layer forward:  (GCNConv -> BN) x2 -> GCNConv
// N=100000, E=1600000, IN=H=128, OUT=64
// Round 8: zero-LDS register MFMA GEMM (pre-transposed f16 W^T, BN fused),
//          counting-sort CSR (bitonic reverted), gather unroll-8 for MLP,
//          stats memsets folded into scan/finalize kernels.
// ---------------------------------------------------------------------------

constexpr int BSH = 7;            // 128 nodes per bucket
constexpr int NXCD = 8;

typedef _Float16 half8 __attribute__((ext_vector_type(8)));
typedef float f32x4 __attribute__((ext_vector_type(4)));

static __device__ inline ushort f2h(float f) {
    union { __half h; ushort u; } cv;
    cv.h = __float2half_rn(f);
    return cv.u;
}
static __device__ inline float2 h2f2(unsigned int u) {
    union { unsigned int u; __half2 h; } cv;
    cv.u = u;
    return __half22float2(cv.h);
}

#define ACC8(base, v) do { float2 _f; \
    _f = h2f2((v).x); acc[(base)+0] += _f.x; acc[(base)+1] += _f.y; \
    _f = h2f2((v).y); acc[(base)+2] += _f.x; acc[(base)+3] += _f.y; \
    _f = h2f2((v).z); acc[(base)+4] += _f.x; acc[(base)+5] += _f.y; \
    _f = h2f2((v).w); acc[(base)+6] += _f.x; acc[(base)+7] += _f.y; \
} while (0)

// ---- phase A: per-xcd bucket histogram + per-node degree ------------------
__global__ __launch_bounds__(256) void count_k(const int* __restrict__ dst,
                                               int* __restrict__ hist,
                                               int* __restrict__ deg,
                                               int E, int EPB, int nbuk) {
    __shared__ int lh[1024];
    for (int i = threadIdx.x; i < nbuk; i += 256) lh[i] = 0;
    __syncthreads();
    const int e0 = blockIdx.x * EPB;
    const int e1 = min(e0 + EPB, E);
    for (int e = e0 + threadIdx.x; e < e1; e += 256) {
        int d = dst[e];
        atomicAdd(&lh[d >> BSH], 1);
        atomicAdd(&deg[d], 1);
    }
    __syncthreads();
    const int xcd = blockIdx.x & (NXCD - 1);
    for (int i = threadIdx.x; i < nbuk; i += 256) {
        int v = lh[i];
        if (v) atomicAdd(&hist[xcd * nbuk + i], v);
    }
}

__global__ void deg_to_dis_k(const int* __restrict__ deg, float* __restrict__ dis, int n) {
    int i = blockIdx.x * blockDim.x + threadIdx.x;
    if (i < n) dis[i] = rsqrtf((float)deg[i] + 1.0f);   // +1 self loop
}

// ---- phase B: scan hist (key order: bucket-major, xcd-minor) --------------
// Also zeroes the BN stats accumulators (sums|sumsq = stats[0..255]).
__global__ __launch_bounds__(256) void scan_hist_k(const int* __restrict__ hist,
                                                   int* __restrict__ cur,
                                                   int* __restrict__ bstart,
                                                   int* __restrict__ row_ptr,
                                                   float* __restrict__ stats,
                                                   int nbuk, int n, int E) {
    stats[threadIdx.x] = 0.f;            // 256 threads cover sums+sumsq
    const int NT = nbuk * NXCD;          // <= 8192 assumed
    const int C = (NT + 255) / 256;      // <= 32
    int vals[32];
    const int tid = threadIdx.x;
    int sum = 0;
#pragma unroll
    for (int k = 0; k < 32; ++k) {
        if (k >= C) break;
        int key = tid * C + k;
        int v = 0;
        if (key < NT) {
            int b = key >> 3, x = key & 7;
            v = hist[x * nbuk + b];
        }
        vals[k] = v;
        sum += v;
    }
    __shared__ int part[256];
    part[tid] = sum;
    __syncthreads();
    for (int off = 1; off < 256; off <<= 1) {
        int t = 0;
        if (tid >= off) t = part[tid - off];
        __syncthreads();
        part[tid] += t;
        __syncthreads();
    }
    int run = (tid == 0) ? 0 : part[tid - 1];
#pragma unroll
    for (int k = 0; k < 32; ++k) {
        if (k >= C) break;
        int key = tid * C + k;
        if (key < NT) {
            int b = key >> 3, x = key & 7;
            cur[x * nbuk + b] = run;
            if (x == 0) bstart[b] = run;
        }
        run += vals[k];
    }
    if (tid == 0) { bstart[nbuk] = E; row_ptr[n] = E; }
}

// ---- phase C: scatter packed edges into (bucket, xcd) segments ------------
__global__ __launch_bounds__(256) void scatter_bucket_k(const int* __restrict__ src,
                                                        const int* __restrict__ dst,
                                                        int* __restrict__ cur,
                                                        unsigned int* __restrict__ ebuf,
                                                        int E, int EPB, int nbuk) {
    const int e0 = blockIdx.x * EPB;
    const int e1 = min(e0 + EPB, E);
    const int xcd = blockIdx.x & (NXCD - 1);
    for (int e = e0 + threadIdx.x; e < e1; e += 256) {
        int d = dst[e];
        int s = src[e];
        int b = d >> BSH;
        int pos = atomicAdd(&cur[xcd * nbuk + b], 1);
        ebuf[pos] = ((unsigned int)s << BSH) | (unsigned int)(d & 127);
    }
}

// ---- phase D: per-bucket LDS counting sort -> per-node esrc + row_ptr -----
__global__ __launch_bounds__(256) void bucket_sort_k(const unsigned int* __restrict__ ebuf,
                                                     const int* __restrict__ bstart,
                                                     int* __restrict__ row_ptr,
                                                     int* __restrict__ esrc, int n) {
    const int b = blockIdx.x;
    const int beg = bstart[b];
    const int end = bstart[b + 1];
    __shared__ int cnt[128], off[128];
    if (threadIdx.x < 128) cnt[threadIdx.x] = 0;
    __syncthreads();
    for (int i = beg + threadIdx.x; i < end; i += 256)
        atomicAdd(&cnt[ebuf[i] & 127], 1);
    __syncthreads();
    if (threadIdx.x < 128) off[threadIdx.x] = cnt[threadIdx.x];
    __syncthreads();
    for (int d = 1; d < 128; d <<= 1) {
        int t = 0;
        if (threadIdx.x < 128 && threadIdx.x >= d) t = off[threadIdx.x - d];
        __syncthreads();
        if (threadIdx.x < 128) off[threadIdx.x] += t;
        __syncthreads();
    }
    if (threadIdx.x < 128) {
        int ex = off[threadIdx.x] - cnt[threadIdx.x];   // exclusive
        int node = (b << BSH) + threadIdx.x;
        if (node < n) row_ptr[node] = beg + ex;
        cnt[threadIdx.x] = ex;                          // reuse as cursor
    }
    __syncthreads();
    for (int i = beg + threadIdx.x; i < end; i += 256) {
        unsigned int p = ebuf[i];
        int l = (int)(p & 127);
        int pos = beg + atomicAdd(&cnt[l], 1);
        esrc[pos] = (int)(p >> BSH);
    }
}

// ---- W^T f16 prep: WT[n][k] = f16(W[k][n]), once per launch ---------------
__global__ __launch_bounds__(256) void prep_wt_k(const float* __restrict__ W1,
                                                 const float* __restrict__ W2,
                                                 const float* __restrict__ W3,
                                                 ushort* __restrict__ wt1,
                                                 ushort* __restrict__ wt2,
                                                 ushort* __restrict__ wt3) {
    const float* W; ushort* WT; int OUTD;
    if (blockIdx.x == 0)      { W = W1; WT = wt1; OUTD = 128; }
    else if (blockIdx.x == 1) { W = W2; WT = wt2; OUTD = 128; }
    else                      { W = W3; WT = wt3; OUTD = 64; }
    const int tot = 128 * OUTD;
    for (int idx = threadIdx.x; idx < tot; idx += 256) {
        int nq = idx >> 7;          // output col
        int k  = idx & 127;         // input k
        WT[idx] = f2h(W[k * OUTD + nq]);
    }
}

// ------- register MFMA GEMM: Hs = f16( (BN(X) @ W) * dis ) -----------------
// Zero LDS. Block = 4 waves x 16 rows = 64 rows. A from global X (BN fused,
// each element read once, full-line segments); B from f16 W^T (L1-resident).
// Hs layout: [NCHUNK][N][32 f16], chunk c holds columns [32c, 32c+32).
template <int OUTD, bool BNIN>
__global__ __launch_bounds__(256) void gemm_reg_k(const float* __restrict__ X,
                                                  const ushort* __restrict__ WT,
                                                  const float* __restrict__ scale,
                                                  const float* __restrict__ shift,
                                                  const float* __restrict__ dis,
                                                  ushort* __restrict__ Hs, int nn) {
    constexpr int NCT = OUTD / 16;       // col tiles: 8 or 4
    const int wave = threadIdx.x >> 6;
    const int lane = threadIdx.x & 63;
    const int l15 = lane & 15;
    const int kg = lane >> 4;            // 0..3
    const int row = blockIdx.x * 64 + wave * 16 + l15;

    // A fragments: row fixed, k = kk*32 + kg*8 + [0..8)
    half8 a[4];
#pragma unroll
    for (int kk = 0; kk < 4; ++kk) {
        if (row < nn) {
            const float4* xp = (const float4*)(X + (size_t)row * 128 + kk * 32 + kg * 8);
            float4 v0 = xp[0];
            float4 v1 = xp[1];
            if (BNIN) {
                int kq = kk * 8 + kg * 2;
                float4 s0 = ((const float4*)scale)[kq];
                float4 s1 = ((const float4*)scale)[kq + 1];
                float4 h0 = ((const float4*)shift)[kq];
                float4 h1 = ((const float4*)shift)[kq + 1];
                v0.x = v0.x * s0.x + h0.x;
                v0.y = v0.y * s0.y + h0.y;
                v0.z = v0.z * s0.z + h0.z;
                v0.w = v0.w * s0.w + h0.w;
                v1.x = v1.x * s1.x + h1.x;
                v1.y = v1.y * s1.y + h1.y;
                v1.z = v1.z * s1.z + h1.z;
                v1.w = v1.w * s1.w + h1.w;
            }
            a[kk][0] = (_Float16)v0.x;
            a[kk][1] = (_Float16)v0.y;
            a[kk][2] = (_Float16)v0.z;
            a[kk][3] = (_Float16)v0.w;
            a[kk][4] = (_Float16)v1.x;
            a[kk][5] = (_Float16)v1.y;
            a[kk][6] = (_Float16)v1.z;
            a[kk][7] = (_Float16)v1.w;
        } else {
#pragma unroll
            for (int j = 0; j < 8; ++j) a[kk][j] = (_Float16)0.f;
        }
    }

    f32x4 acc[NCT];
#pragma unroll
    for (int ct = 0; ct < NCT; ++ct) acc[ct] = (f32x4){0.f, 0.f, 0.f, 0.f};

#pragma unroll
    for (int kk = 0; kk < 4; ++kk) {
#pragma unroll
        for (int ct = 0; ct < NCT; ++ct) {
            half8 bfr = *(const half8*)&WT[(ct * 16 + l15) * 128 + kk * 32 + kg * 8];
            acc[ct] = __builtin_amdgcn_mfma_f32_16x16x32_f16(a[kk], bfr, acc[ct], 0, 0, 0);
        }
    }

    // D: col = lane&15 (within ct), row = kg*4 + reg (within wave tile)
    const int mbase = blockIdx.x * 64 + wave * 16 + kg * 4;
    float dm[4];
#pragma unroll
    for (int reg = 0; reg < 4; ++reg) {
        int m = mbase + reg;
        dm[reg] = (m < nn) ? dis[m] : 0.f;
    }
#pragma unroll
    for (int ct = 0; ct < NCT; ++ct) {
        int ncol = ct * 16 + l15;
        size_t cb = (size_t)(ncol >> 5) * nn * 32 + (ncol & 31);
#pragma unroll
        for (int reg = 0; reg < 4; ++reg) {
            int m = mbase + reg;
            if (m < nn) Hs[cb + (size_t)m * 32] = f2h(acc[ct][reg] * dm[reg]);
        }
    }
}

// ---------------- chunked gather aggregation (+ fused BN stats) ------------
// Per chunk c (32 cols): O[i][32c..32c+32) = dis[i]*(Hs_c[i] + sum Hs_c[src]) + b
// 2 lanes per 64B row; unroll-8 software pipeline (16 loads in flight/thread).
template <int OUTD, bool STATS>
__global__ __launch_bounds__(256) void gather_k(const ushort* __restrict__ Hs,
                                                const float* __restrict__ dis,
                                                const float* __restrict__ b,
                                                const int* __restrict__ row_ptr,
                                                const int* __restrict__ esrc,
                                                float* __restrict__ O,
                                                float* __restrict__ sums,
                                                float* __restrict__ sumsq, int n) {
    constexpr int NCHUNK = OUTD / 32;   // 4 or 2

    __shared__ float s_sum[32];
    __shared__ float s_sq[32];
    if (STATS) {
        if (threadIdx.x < 32) { s_sum[threadIdx.x] = 0.f; s_sq[threadIdx.x] = 0.f; }
        __syncthreads();
    }

    const int chunk = blockIdx.x & (NCHUNK - 1);
    const int nblk  = blockIdx.x / NCHUNK;
    const int g     = threadIdx.x >> 1;     // node within block: 0..127
    const int lane  = threadIdx.x & 1;      // which half of the 64B row
    const int node  = nblk * 128 + g;

    float acc[16];
#pragma unroll
    for (int c = 0; c < 16; ++c) acc[c] = 0.f;
    float o[16];
#pragma unroll
    for (int c = 0; c < 16; ++c) o[c] = 0.f;

    if (node < n) {
        const uint4* Hc = (const uint4*)Hs + (size_t)chunk * n * 4;  // 4 uint4/node

        {   // self row (dis pre-folded into Hs)
            uint4 v0 = Hc[(size_t)node * 4 + lane];
            uint4 v1 = Hc[(size_t)node * 4 + lane + 2];
            ACC8(0, v0);
            ACC8(8, v1);
        }
        const int beg = row_ptr[node];
        const int end = row_ptr[node + 1];
        int j = beg;
        const int end8 = beg + ((end - beg) & ~7);
        for (; j < end8; j += 8) {
            int s[8];
#pragma unroll
            for (int u = 0; u < 8; ++u) s[u] = esrc[j + u];
            uint4 va[8], vb[8];
#pragma unroll
            for (int u = 0; u < 8; ++u) va[u] = Hc[(size_t)s[u] * 4 + lane];
#pragma unroll
            for (int u = 0; u < 8; ++u) vb[u] = Hc[(size_t)s[u] * 4 + lane + 2];
#pragma unroll
            for (int u = 0; u < 8; ++u) { ACC8(0, va[u]); }
#pragma unroll
            for (int u = 0; u < 8; ++u) { ACC8(8, vb[u]); }
        }
        for (; j < end; ++j) {
            int s = esrc[j];
            uint4 a = Hc[(size_t)s * 4 + lane];
            uint4 c = Hc[(size_t)s * 4 + lane + 2];
            ACC8(0, a);
            ACC8(8, c);
        }

        float dd = dis[node];
        const float4* B4 = (const float4*)b + chunk * 8 + lane * 2;
        float4 b0 = B4[0];
        float4 b1 = B4[1];
        float4 b2 = B4[4];
        float4 b3 = B4[5];
        o[0]  = acc[0]  * dd + b0.x;
        o[1]  = acc[1]  * dd + b0.y;
        o[2]  = acc[2]  * dd + b0.z;
        o[3]  = acc[3]  * dd + b0.w;
        o[4]  = acc[4]  * dd + b1.x;
        o[5]  = acc[5]  * dd + b1.y;
        o[6]  = acc[6]  * dd + b1.z;
        o[7]  = acc[7]  * dd + b1.w;
        o[8]  = acc[8]  * dd + b2.x;
        o[9]  = acc[9]  * dd + b2.y;
        o[10] = acc[10] * dd + b2.z;
        o[11] = acc[11] * dd + b2.w;
        o[12] = acc[12] * dd + b3.x;
        o[13] = acc[13] * dd + b3.y;
        o[14] = acc[14] * dd + b3.z;
        o[15] = acc[15] * dd + b3.w;

        float4* O4 = (float4*)O + (size_t)node * (OUTD / 4) + chunk * 8 + lane * 2;
        O4[0] = make_float4(o[0], o[1], o[2], o[3]);
        O4[1] = make_float4(o[4], o[5], o[6], o[7]);
        O4[4] = make_float4(o[8], o[9], o[10], o[11]);
        O4[5] = make_float4(o[12], o[13], o[14], o[15]);
    }

    if (STATS) {
        // lanes of equal parity (lane&1) hold the same 16 columns for 32 nodes
        float sv[16], qv[16];
#pragma unroll
        for (int c = 0; c < 16; ++c) { sv[c] = o[c]; qv[c] = o[c] * o[c]; }
#pragma unroll
        for (int c = 0; c < 16; ++c) {
#pragma unroll
            for (int m = 2; m <= 32; m <<= 1) {
                sv[c] += __shfl_xor(sv[c], m);
                qv[c] += __shfl_xor(qv[c], m);
            }
        }
        if ((threadIdx.x & 63) < 2) {
            // lane 0: cols 0-7 and 16-23 of chunk; lane 1: cols 8-15 and 24-31
            int c0 = lane * 8;
            int c1 = 16 + lane * 8;
#pragma unroll
            for (int c = 0; c < 8; ++c) {
                atomicAdd(&s_sum[c0 + c], sv[c]);
                atomicAdd(&s_sq[c0 + c], qv[c]);
                atomicAdd(&s_sum[c1 + c], sv[8 + c]);
                atomicAdd(&s_sq[c1 + c], qv[8 + c]);
            }
        }
        __syncthreads();
        if (threadIdx.x < 32) {
            atomicAdd(&sums[chunk * 32 + threadIdx.x], s_sum[threadIdx.x]);
            atomicAdd(&sumsq[chunk * 32 + threadIdx.x], s_sq[threadIdx.x]);
        }
    }
}

// ---- BN finalize: scale/shift from sums; self-zeroes stats for next layer -
__global__ void bn_finalize_k(float* __restrict__ sums, float* __restrict__ sumsq,
                              const float* __restrict__ g, const float* __restrict__ be,
                              float* __restrict__ scale, float* __restrict__ shift, int n) {
    int c = threadIdx.x;  // 128 threads
    float inv_n = 1.0f / (float)n;
    float m = sums[c] * inv_n;
    float v = sumsq[c] * inv_n - m * m;
    float sc = rsqrtf(v + 1e-5f) * g[c];
    scale[c] = sc;
    shift[c] = be[c] - m * sc;
    sums[c] = 0.f;
    sumsq[c] = 0.f;
}

// ---------------------------------------------------------------------------
extern "C" void kernel_launch(void* const* d_in, const int* in_sizes, int n_in,
                              void* d_out, int out_size, void* d_ws, size_t ws_size,
                              hipStream_t stream) {
    const float* x   = (const float*)d_in[0];
    const int*   ei  = (const int*)d_in[1];
    const float* W1  = (const float*)d_in[2];
    const float* b1  = (const float*)d_in[3];
    const float* g1  = (const float*)d_in[4];
    const float* be1 = (const float*)d_in[5];
    const float* W2  = (const float*)d_in[6];
    const float* b2  = (const float*)d_in[7];
    const float* g2  = (const float*)d_in[8];
    const float* be2 = (const float*)d_in[9];
    const float* W3  = (const float*)d_in[10];
    const float* b3  = (const float*)d_in[11];
    float* out = (float*)d_out;

    const int N = in_sizes[0] / 128;
    const int E = in_sizes[1] / 2;
    const int* src = ei;
    const int* dst = ei + E;
    const int NBUK = (N + 127) >> BSH;

    // ---- workspace layout ----
    float* wsp   = (float*)d_ws;
    float* dis   = wsp;                               // N f32
    float* stats = wsp + N;                           // 512 f32
    ushort* wt1  = (ushort*)(stats + 512);            // 128*128 f16
    ushort* wt2  = wt1 + 128 * 128;
    ushort* wt3  = wt2 + 128 * 128;                   // 128*64 f16
    int*   hist   = (int*)(wt3 + 128 * 64);           // NBUK*8
    int*   cur    = hist + NBUK * NXCD;               // NBUK*8
    int*   bstart = cur + NBUK * NXCD;                // NBUK+1
    int*   row_ptr = bstart + NBUK + 1 + 63;          // N+1
    float* bufA  = (float*)((((uintptr_t)(row_ptr + N + 1)) + 255) & ~(uintptr_t)255);
    float* bufB  = bufA + (size_t)N * 128;            // N*128 f32 (agg out)
    unsigned int* ebuf = (unsigned int*)(bufB + (size_t)N * 128);  // E u32
    int*   esrc  = (int*)(ebuf + E);                  // E int

    ushort* Hs = (ushort*)bufA;                       // [NCHUNK][N][32] f16
    int* deg = (int*)bufA;                            // N ints (pre-GEMM only)

    float* sums  = stats;
    float* sumsq = stats + 128;
    float* scale = stats + 256;
    float* shift = stats + 384;

    const int BS = 256;
    dim3 blk(BS);
    const int NB = (N + 255) / 256;
    const int SGRID = 512;                 // count/scatter blocks (multiple of 8)
    const int EPB = (E + SGRID - 1) / SGRID;

    // ---- bucket-sorted CSR build ----
    hipMemsetAsync(deg, 0, (size_t)N * 4, stream);
    hipMemsetAsync(hist, 0, (size_t)NBUK * NXCD * 4, stream);
    prep_wt_k<<<dim3(3), blk, 0, stream>>>(W1, W2, W3, wt1, wt2, wt3);
    count_k<<<dim3(SGRID), blk, 0, stream>>>(dst, hist, deg, E, EPB, NBUK);
    deg_to_dis_k<<<dim3(NB), blk, 0, stream>>>(deg, dis, N);
    scan_hist_k<<<dim3(1), blk, 0, stream>>>(hist, cur, bstart, row_ptr, stats, NBUK, N, E);
    scatter_bucket_k<<<dim3(SGRID), blk, 0, stream>>>(src, dst, cur, ebuf, E, EPB, NBUK);
    bucket_sort_k<<<dim3(NBUK), blk, 0, stream>>>(ebuf, bstart, row_ptr, esrc, N);

    const int gemm_grid = (N + 63) / 64;
    const int NBg = (N + 127) / 128;    // gather node-blocks (128 nodes/block)

    // ---- layer 1 ----
    gemm_reg_k<128, false><<<dim3(gemm_grid), blk, 0, stream>>>(x, wt1, nullptr, nullptr,
                                                                dis, Hs, N);
    gather_k<128, true><<<dim3(NBg * 4), blk, 0, stream>>>(Hs, dis, b1, row_ptr, esrc,
                                                           bufB, sums, sumsq, N);
    bn_finalize_k<<<dim3(1), dim3(128), 0, stream>>>(sums, sumsq, g1, be1, scale, shift, N);

    // ---- layer 2 (BN applied inside GEMM A-fragment load) ----
    gemm_reg_k<128, true><<<dim3(gemm_grid), blk, 0, stream>>>(bufB, wt2, scale, shift,
                                                               dis, Hs, N);
    gather_k<128, true><<<dim3(NBg * 4), blk, 0, stream>>>(Hs, dis, b2, row_ptr, esrc,
                                                           bufB, sums, sumsq, N);
    bn_finalize_k<<<dim3(1), dim3(128), 0, stream>>>(sums, sumsq, g2, be2, scale, shift, N);

    // ---- layer 3 (OUT = 64, straight to d_out) ----
    gemm_reg_k<64, true><<<dim3(gemm_grid), blk, 0, stream>>>(bufB, wt3, scale, shift,
                                                              dis, Hs, N);
    gather_k<64, false><<<dim3(NBg * 2), blk, 0, stream>>>(Hs, dis, b3, row_ptr, esrc,
                                                           out, nullptr, nullptr, N);
}

// Round 10
// 453.458 us; speedup vs baseline: 1.5634x; 1.3142x over previous
//
#include <hip/hip_runtime.h>
#include <hip/hip_fp16.h>

// ---------------------------------------------------------------------------
// GCN 3-layer forward:  (GCNConv -> BN) x2 -> GCNConv
// N=100000, E=1600000, IN=H=128, OUT=64
// Round 9: two-pass LDS-aggregated bucket scatter (global atomics 1.6M->100K,
//          full-line ebuf writes), deg from row_ptr (no per-node atomics).
//          Gather (unroll-8) and reg-MFMA GEMM unchanged from round 8.
// ---------------------------------------------------------------------------

constexpr int BSH = 7;            // 128 nodes per bucket
constexpr int NXCD = 8;

typedef _Float16 half8 __attribute__((ext_vector_type(8)));
typedef float f32x4 __attribute__((ext_vector_type(4)));

static __device__ inline ushort f2h(float f) {
    union { __half h; ushort u; } cv;
    cv.h = __float2half_rn(f);
    return cv.u;
}
static __device__ inline float2 h2f2(unsigned int u) {
    union { unsigned int u; __half2 h; } cv;
    cv.u = u;
    return __half22float2(cv.h);
}

#define ACC8(base, v) do { float2 _f; \
    _f = h2f2((v).x); acc[(base)+0] += _f.x; acc[(base)+1] += _f.y; \
    _f = h2f2((v).y); acc[(base)+2] += _f.x; acc[(base)+3] += _f.y; \
    _f = h2f2((v).z); acc[(base)+4] += _f.x; acc[(base)+5] += _f.y; \
    _f = h2f2((v).w); acc[(base)+6] += _f.x; acc[(base)+7] += _f.y; \
} while (0)

// ---- phase A: per-xcd bucket histogram (LDS-aggregated) -------------------
__global__ __launch_bounds__(256) void count_k(const int* __restrict__ dst,
                                               int* __restrict__ hist,
                                               int E, int EPB, int nbuk) {
    __shared__ int lh[1024];
    for (int i = threadIdx.x; i < nbuk; i += 256) lh[i] = 0;
    __syncthreads();
    const int e0 = blockIdx.x * EPB;
    const int e1 = min(e0 + EPB, E);
    for (int e = e0 + threadIdx.x; e < e1; e += 256)
        atomicAdd(&lh[dst[e] >> BSH], 1);
    __syncthreads();
    const int xcd = blockIdx.x & (NXCD - 1);
    for (int i = threadIdx.x; i < nbuk; i += 256) {
        int v = lh[i];
        if (v) atomicAdd(&hist[xcd * nbuk + i], v);
    }
}

// ---- phase B: scan hist (key order: bucket-major, xcd-minor) --------------
// Also zeroes the BN stats accumulators (sums|sumsq = stats[0..255]).
__global__ __launch_bounds__(256) void scan_hist_k(const int* __restrict__ hist,
                                                   int* __restrict__ cur,
                                                   int* __restrict__ bstart,
                                                   int* __restrict__ row_ptr,
                                                   float* __restrict__ stats,
                                                   int nbuk, int n, int E) {
    stats[threadIdx.x] = 0.f;            // 256 threads cover sums+sumsq
    const int NT = nbuk * NXCD;          // <= 8192 assumed
    const int C = (NT + 255) / 256;      // <= 32
    int vals[32];
    const int tid = threadIdx.x;
    int sum = 0;
#pragma unroll
    for (int k = 0; k < 32; ++k) {
        if (k >= C) break;
        int key = tid * C + k;
        int v = 0;
        if (key < NT) {
            int b = key >> 3, x = key & 7;
            v = hist[x * nbuk + b];
        }
        vals[k] = v;
        sum += v;
    }
    __shared__ int part[256];
    part[tid] = sum;
    __syncthreads();
    for (int off = 1; off < 256; off <<= 1) {
        int t = 0;
        if (tid >= off) t = part[tid - off];
        __syncthreads();
        part[tid] += t;
        __syncthreads();
    }
    int run = (tid == 0) ? 0 : part[tid - 1];
#pragma unroll
    for (int k = 0; k < 32; ++k) {
        if (k >= C) break;
        int key = tid * C + k;
        if (key < NT) {
            int b = key >> 3, x = key & 7;
            cur[x * nbuk + b] = run;
            if (x == 0) bstart[b] = run;
        }
        run += vals[k];
    }
    if (tid == 0) { bstart[nbuk] = E; row_ptr[n] = E; }
}

// ---- phase C: two-pass LDS-aggregated scatter into (bucket, xcd) segments -
// Pass 1: LDS histogram; reserve one global atomic per (block, nonzero bucket)
// Pass 2: place edges via LDS cursor -> ~EPB/nbuk consecutive entries/bucket.
__global__ __launch_bounds__(256) void scatter_bucket_k(const int* __restrict__ src,
                                                        const int* __restrict__ dst,
                                                        int* __restrict__ cur,
                                                        unsigned int* __restrict__ ebuf,
                                                        int E, int EPB, int nbuk) {
    __shared__ int lh[1024];
    __shared__ int base[1024];
    for (int i = threadIdx.x; i < nbuk; i += 256) lh[i] = 0;
    __syncthreads();
    const int e0 = blockIdx.x * EPB;
    const int e1 = min(e0 + EPB, E);
    const int xcd = blockIdx.x & (NXCD - 1);
    for (int e = e0 + threadIdx.x; e < e1; e += 256)
        atomicAdd(&lh[dst[e] >> BSH], 1);
    __syncthreads();
    for (int i = threadIdx.x; i < nbuk; i += 256) {
        int v = lh[i];
        base[i] = v ? atomicAdd(&cur[xcd * nbuk + i], v) : 0;
        lh[i] = 0;                      // becomes cursor
    }
    __syncthreads();
    for (int e = e0 + threadIdx.x; e < e1; e += 256) {
        int d = dst[e];
        int s = src[e];
        int b = d >> BSH;
        int pos = base[b] + atomicAdd(&lh[b], 1);
        ebuf[pos] = ((unsigned int)s << BSH) | (unsigned int)(d & 127);
    }
}

// ---- phase D: per-bucket LDS counting sort -> per-node esrc + row_ptr -----
__global__ __launch_bounds__(256) void bucket_sort_k(const unsigned int* __restrict__ ebuf,
                                                     const int* __restrict__ bstart,
                                                     int* __restrict__ row_ptr,
                                                     int* __restrict__ esrc, int n) {
    const int b = blockIdx.x;
    const int beg = bstart[b];
    const int end = bstart[b + 1];
    __shared__ int cnt[128], off[128];
    if (threadIdx.x < 128) cnt[threadIdx.x] = 0;
    __syncthreads();
    for (int i = beg + threadIdx.x; i < end; i += 256)
        atomicAdd(&cnt[ebuf[i] & 127], 1);
    __syncthreads();
    if (threadIdx.x < 128) off[threadIdx.x] = cnt[threadIdx.x];
    __syncthreads();
    for (int d = 1; d < 128; d <<= 1) {
        int t = 0;
        if (threadIdx.x < 128 && threadIdx.x >= d) t = off[threadIdx.x - d];
        __syncthreads();
        if (threadIdx.x < 128) off[threadIdx.x] += t;
        __syncthreads();
    }
    if (threadIdx.x < 128) {
        int ex = off[threadIdx.x] - cnt[threadIdx.x];   // exclusive
        int node = (b << BSH) + threadIdx.x;
        if (node < n) row_ptr[node] = beg + ex;
        cnt[threadIdx.x] = ex;                          // reuse as cursor
    }
    __syncthreads();
    for (int i = beg + threadIdx.x; i < end; i += 256) {
        unsigned int p = ebuf[i];
        int l = (int)(p & 127);
        int pos = beg + atomicAdd(&cnt[l], 1);
        esrc[pos] = (int)(p >> BSH);
    }
}

// ---- dis from row_ptr diffs (replaces per-node deg atomics) ---------------
__global__ void rowptr_to_dis_k(const int* __restrict__ row_ptr,
                                float* __restrict__ dis, int n) {
    int i = blockIdx.x * blockDim.x + threadIdx.x;
    if (i < n) {
        int deg = row_ptr[i + 1] - row_ptr[i];
        dis[i] = rsqrtf((float)deg + 1.0f);   // +1 self loop
    }
}

// ---- W^T f16 prep: WT[n][k] = f16(W[k][n]), once per launch ---------------
__global__ __launch_bounds__(256) void prep_wt_k(const float* __restrict__ W1,
                                                 const float* __restrict__ W2,
                                                 const float* __restrict__ W3,
                                                 ushort* __restrict__ wt1,
                                                 ushort* __restrict__ wt2,
                                                 ushort* __restrict__ wt3) {
    const float* W; ushort* WT; int OUTD;
    if (blockIdx.x == 0)      { W = W1; WT = wt1; OUTD = 128; }
    else if (blockIdx.x == 1) { W = W2; WT = wt2; OUTD = 128; }
    else                      { W = W3; WT = wt3; OUTD = 64; }
    const int tot = 128 * OUTD;
    for (int idx = threadIdx.x; idx < tot; idx += 256) {
        int nq = idx >> 7;          // output col
        int k  = idx & 127;         // input k
        WT[idx] = f2h(W[k * OUTD + nq]);
    }
}

// ------- register MFMA GEMM: Hs = f16( (BN(X) @ W) * dis ) -----------------
// Zero LDS. Block = 4 waves x 16 rows = 64 rows. A from global X (BN fused,
// each element read once, full-line segments); B from f16 W^T (L1-resident).
// Hs layout: [NCHUNK][N][32 f16], chunk c holds columns [32c, 32c+32).
template <int OUTD, bool BNIN>
__global__ __launch_bounds__(256) void gemm_reg_k(const float* __restrict__ X,
                                                  const ushort* __restrict__ WT,
                                                  const float* __restrict__ scale,
                                                  const float* __restrict__ shift,
                                                  const float* __restrict__ dis,
                                                  ushort* __restrict__ Hs, int nn) {
    constexpr int NCT = OUTD / 16;       // col tiles: 8 or 4
    const int wave = threadIdx.x >> 6;
    const int lane = threadIdx.x & 63;
    const int l15 = lane & 15;
    const int kg = lane >> 4;            // 0..3
    const int row = blockIdx.x * 64 + wave * 16 + l15;

    // A fragments: row fixed, k = kk*32 + kg*8 + [0..8)
    half8 a[4];
#pragma unroll
    for (int kk = 0; kk < 4; ++kk) {
        if (row < nn) {
            const float4* xp = (const float4*)(X + (size_t)row * 128 + kk * 32 + kg * 8);
            float4 v0 = xp[0];
            float4 v1 = xp[1];
            if (BNIN) {
                int kq = kk * 8 + kg * 2;
                float4 s0 = ((const float4*)scale)[kq];
                float4 s1 = ((const float4*)scale)[kq + 1];
                float4 h0 = ((const float4*)shift)[kq];
                float4 h1 = ((const float4*)shift)[kq + 1];
                v0.x = v0.x * s0.x + h0.x;
                v0.y = v0.y * s0.y + h0.y;
                v0.z = v0.z * s0.z + h0.z;
                v0.w = v0.w * s0.w + h0.w;
                v1.x = v1.x * s1.x + h1.x;
                v1.y = v1.y * s1.y + h1.y;
                v1.z = v1.z * s1.z + h1.z;
                v1.w = v1.w * s1.w + h1.w;
            }
            a[kk][0] = (_Float16)v0.x;
            a[kk][1] = (_Float16)v0.y;
            a[kk][2] = (_Float16)v0.z;
            a[kk][3] = (_Float16)v0.w;
            a[kk][4] = (_Float16)v1.x;
            a[kk][5] = (_Float16)v1.y;
            a[kk][6] = (_Float16)v1.z;
            a[kk][7] = (_Float16)v1.w;
        } else {
#pragma unroll
            for (int j = 0; j < 8; ++j) a[kk][j] = (_Float16)0.f;
        }
    }

    f32x4 acc[NCT];
#pragma unroll
    for (int ct = 0; ct < NCT; ++ct) acc[ct] = (f32x4){0.f, 0.f, 0.f, 0.f};

#pragma unroll
    for (int kk = 0; kk < 4; ++kk) {
#pragma unroll
        for (int ct = 0; ct < NCT; ++ct) {
            half8 bfr = *(const half8*)&WT[(ct * 16 + l15) * 128 + kk * 32 + kg * 8];
            acc[ct] = __builtin_amdgcn_mfma_f32_16x16x32_f16(a[kk], bfr, acc[ct], 0, 0, 0);
        }
    }

    // D: col = lane&15 (within ct), row = kg*4 + reg (within wave tile)
    const int mbase = blockIdx.x * 64 + wave * 16 + kg * 4;
    float dm[4];
#pragma unroll
    for (int reg = 0; reg < 4; ++reg) {
        int m = mbase + reg;
        dm[reg] = (m < nn) ? dis[m] : 0.f;
    }
#pragma unroll
    for (int ct = 0; ct < NCT; ++ct) {
        int ncol = ct * 16 + l15;
        size_t cb = (size_t)(ncol >> 5) * nn * 32 + (ncol & 31);
#pragma unroll
        for (int reg = 0; reg < 4; ++reg) {
            int m = mbase + reg;
            if (m < nn) Hs[cb + (size_t)m * 32] = f2h(acc[ct][reg] * dm[reg]);
        }
    }
}

// ---------------- chunked gather aggregation (+ fused BN stats) ------------
// Per chunk c (32 cols): O[i][32c..32c+32) = dis[i]*(Hs_c[i] + sum Hs_c[src]) + b
// 2 lanes per 64B row; unroll-8 software pipeline (16 loads in flight/thread).
template <int OUTD, bool STATS>
__global__ __launch_bounds__(256) void gather_k(const ushort* __restrict__ Hs,
                                                const float* __restrict__ dis,
                                                const float* __restrict__ b,
                                                const int* __restrict__ row_ptr,
                                                const int* __restrict__ esrc,
                                                float* __restrict__ O,
                                                float* __restrict__ sums,
                                                float* __restrict__ sumsq, int n) {
    constexpr int NCHUNK = OUTD / 32;   // 4 or 2

    __shared__ float s_sum[32];
    __shared__ float s_sq[32];
    if (STATS) {
        if (threadIdx.x < 32) { s_sum[threadIdx.x] = 0.f; s_sq[threadIdx.x] = 0.f; }
        __syncthreads();
    }

    const int chunk = blockIdx.x & (NCHUNK - 1);
    const int nblk  = blockIdx.x / NCHUNK;
    const int g     = threadIdx.x >> 1;     // node within block: 0..127
    const int lane  = threadIdx.x & 1;      // which half of the 64B row
    const int node  = nblk * 128 + g;

    float acc[16];
#pragma unroll
    for (int c = 0; c < 16; ++c) acc[c] = 0.f;
    float o[16];
#pragma unroll
    for (int c = 0; c < 16; ++c) o[c] = 0.f;

    if (node < n) {
        const uint4* Hc = (const uint4*)Hs + (size_t)chunk * n * 4;  // 4 uint4/node

        {   // self row (dis pre-folded into Hs)
            uint4 v0 = Hc[(size_t)node * 4 + lane];
            uint4 v1 = Hc[(size_t)node * 4 + lane + 2];
            ACC8(0, v0);
            ACC8(8, v1);
        }
        const int beg = row_ptr[node];
        const int end = row_ptr[node + 1];
        int j = beg;
        const int end8 = beg + ((end - beg) & ~7);
        for (; j < end8; j += 8) {
            int s[8];
#pragma unroll
            for (int u = 0; u < 8; ++u) s[u] = esrc[j + u];
            uint4 va[8], vb[8];
#pragma unroll
            for (int u = 0; u < 8; ++u) va[u] = Hc[(size_t)s[u] * 4 + lane];
#pragma unroll
            for (int u = 0; u < 8; ++u) vb[u] = Hc[(size_t)s[u] * 4 + lane + 2];
#pragma unroll
            for (int u = 0; u < 8; ++u) { ACC8(0, va[u]); }
#pragma unroll
            for (int u = 0; u < 8; ++u) { ACC8(8, vb[u]); }
        }
        for (; j < end; ++j) {
            int s = esrc[j];
            uint4 a = Hc[(size_t)s * 4 + lane];
            uint4 c = Hc[(size_t)s * 4 + lane + 2];
            ACC8(0, a);
            ACC8(8, c);
        }

        float dd = dis[node];
        const float4* B4 = (const float4*)b + chunk * 8 + lane * 2;
        float4 b0 = B4[0];
        float4 b1 = B4[1];
        float4 b2 = B4[4];
        float4 b3 = B4[5];
        o[0]  = acc[0]  * dd + b0.x;
        o[1]  = acc[1]  * dd + b0.y;
        o[2]  = acc[2]  * dd + b0.z;
        o[3]  = acc[3]  * dd + b0.w;
        o[4]  = acc[4]  * dd + b1.x;
        o[5]  = acc[5]  * dd + b1.y;
        o[6]  = acc[6]  * dd + b1.z;
        o[7]  = acc[7]  * dd + b1.w;
        o[8]  = acc[8]  * dd + b2.x;
        o[9]  = acc[9]  * dd + b2.y;
        o[10] = acc[10] * dd + b2.z;
        o[11] = acc[11] * dd + b2.w;
        o[12] = acc[12] * dd + b3.x;
        o[13] = acc[13] * dd + b3.y;
        o[14] = acc[14] * dd + b3.z;
        o[15] = acc[15] * dd + b3.w;

        float4* O4 = (float4*)O + (size_t)node * (OUTD / 4) + chunk * 8 + lane * 2;
        O4[0] = make_float4(o[0], o[1], o[2], o[3]);
        O4[1] = make_float4(o[4], o[5], o[6], o[7]);
        O4[4] = make_float4(o[8], o[9], o[10], o[11]);
        O4[5] = make_float4(o[12], o[13], o[14], o[15]);
    }

    if (STATS) {
        // lanes of equal parity (lane&1) hold the same 16 columns for 32 nodes
        float sv[16], qv[16];
#pragma unroll
        for (int c = 0; c < 16; ++c) { sv[c] = o[c]; qv[c] = o[c] * o[c]; }
#pragma unroll
        for (int c = 0; c < 16; ++c) {
#pragma unroll
            for (int m = 2; m <= 32; m <<= 1) {
                sv[c] += __shfl_xor(sv[c], m);
                qv[c] += __shfl_xor(qv[c], m);
            }
        }
        if ((threadIdx.x & 63) < 2) {
            // lane 0: cols 0-7 and 16-23 of chunk; lane 1: cols 8-15 and 24-31
            int c0 = lane * 8;
            int c1 = 16 + lane * 8;
#pragma unroll
            for (int c = 0; c < 8; ++c) {
                atomicAdd(&s_sum[c0 + c], sv[c]);
                atomicAdd(&s_sq[c0 + c], qv[c]);
                atomicAdd(&s_sum[c1 + c], sv[8 + c]);
                atomicAdd(&s_sq[c1 + c], qv[8 + c]);
            }
        }
        __syncthreads();
        if (threadIdx.x < 32) {
            atomicAdd(&sums[chunk * 32 + threadIdx.x], s_sum[threadIdx.x]);
            atomicAdd(&sumsq[chunk * 32 + threadIdx.x], s_sq[threadIdx.x]);
        }
    }
}

// ---- BN finalize: scale/shift from sums; self-zeroes stats for next layer -
__global__ void bn_finalize_k(float* __restrict__ sums, float* __restrict__ sumsq,
                              const float* __restrict__ g, const float* __restrict__ be,
                              float* __restrict__ scale, float* __restrict__ shift, int n) {
    int c = threadIdx.x;  // 128 threads
    float inv_n = 1.0f / (float)n;
    float m = sums[c] * inv_n;
    float v = sumsq[c] * inv_n - m * m;
    float sc = rsqrtf(v + 1e-5f) * g[c];
    scale[c] = sc;
    shift[c] = be[c] - m * sc;
    sums[c] = 0.f;
    sumsq[c] = 0.f;
}

// ---------------------------------------------------------------------------
extern "C" void kernel_launch(void* const* d_in, const int* in_sizes, int n_in,
                              void* d_out, int out_size, void* d_ws, size_t ws_size,
                              hipStream_t stream) {
    const float* x   = (const float*)d_in[0];
    const int*   ei  = (const int*)d_in[1];
    const float* W1  = (const float*)d_in[2];
    const float* b1  = (const float*)d_in[3];
    const float* g1  = (const float*)d_in[4];
    const float* be1 = (const float*)d_in[5];
    const float* W2  = (const float*)d_in[6];
    const float* b2  = (const float*)d_in[7];
    const float* g2  = (const float*)d_in[8];
    const float* be2 = (const float*)d_in[9];
    const float* W3  = (const float*)d_in[10];
    const float* b3  = (const float*)d_in[11];
    float* out = (float*)d_out;

    const int N = in_sizes[0] / 128;
    const int E = in_sizes[1] / 2;
    const int* src = ei;
    const int* dst = ei + E;
    const int NBUK = (N + 127) >> BSH;

    // ---- workspace layout ----
    float* wsp   = (float*)d_ws;
    float* dis   = wsp;                               // N f32
    float* stats = wsp + N;                           // 512 f32
    ushort* wt1  = (ushort*)(stats + 512);            // 128*128 f16
    ushort* wt2  = wt1 + 128 * 128;
    ushort* wt3  = wt2 + 128 * 128;                   // 128*64 f16
    int*   hist   = (int*)(wt3 + 128 * 64);           // NBUK*8
    int*   cur    = hist + NBUK * NXCD;               // NBUK*8
    int*   bstart = cur + NBUK * NXCD;                // NBUK+1
    int*   row_ptr = bstart + NBUK + 1 + 63;          // N+1
    float* bufA  = (float*)((((uintptr_t)(row_ptr + N + 1)) + 255) & ~(uintptr_t)255);
    float* bufB  = bufA + (size_t)N * 128;            // N*128 f32 (agg out)
    unsigned int* ebuf = (unsigned int*)(bufB + (size_t)N * 128);  // E u32
    int*   esrc  = (int*)(ebuf + E);                  // E int

    ushort* Hs = (ushort*)bufA;                       // [NCHUNK][N][32] f16

    float* sums  = stats;
    float* sumsq = stats + 128;
    float* scale = stats + 256;
    float* shift = stats + 384;

    const int BS = 256;
    dim3 blk(BS);
    const int NB = (N + 255) / 256;
    const int SGRID = 128;                 // count/scatter blocks (multiple of 8)
    const int EPB = (E + SGRID - 1) / SGRID;

    // ---- bucket-sorted CSR build ----
    hipMemsetAsync(hist, 0, (size_t)NBUK * NXCD * 4, stream);
    prep_wt_k<<<dim3(3), blk, 0, stream>>>(W1, W2, W3, wt1, wt2, wt3);
    count_k<<<dim3(SGRID), blk, 0, stream>>>(dst, hist, E, EPB, NBUK);
    scan_hist_k<<<dim3(1), blk, 0, stream>>>(hist, cur, bstart, row_ptr, stats, NBUK, N, E);
    scatter_bucket_k<<<dim3(SGRID), blk, 0, stream>>>(src, dst, cur, ebuf, E, EPB, NBUK);
    bucket_sort_k<<<dim3(NBUK), blk, 0, stream>>>(ebuf, bstart, row_ptr, esrc, N);
    rowptr_to_dis_k<<<dim3(NB), blk, 0, stream>>>(row_ptr, dis, N);

    const int gemm_grid = (N + 63) / 64;
    const int NBg = (N + 127) / 128;    // gather node-blocks (128 nodes/block)

    // ---- layer 1 ----
    gemm_reg_k<128, false><<<dim3(gemm_grid), blk, 0, stream>>>(x, wt1, nullptr, nullptr,
                                                                dis, Hs, N);
    gather_k<128, true><<<dim3(NBg * 4), blk, 0, stream>>>(Hs, dis, b1, row_ptr, esrc,
                                                           bufB, sums, sumsq, N);
    bn_finalize_k<<<dim3(1), dim3(128), 0, stream>>>(sums, sumsq, g1, be1, scale, shift, N);

    // ---- layer 2 (BN applied inside GEMM A-fragment load) ----
    gemm_reg_k<128, true><<<dim3(gemm_grid), blk, 0, stream>>>(bufB, wt2, scale, shift,
                                                               dis, Hs, N);
    gather_k<128, true><<<dim3(NBg * 4), blk, 0, stream>>>(Hs, dis, b2, row_ptr, esrc,
                                                           bufB, sums, sumsq, N);
    bn_finalize_k<<<dim3(1), dim3(128), 0, stream>>>(sums, sumsq, g2, be2, scale, shift, N);

    // ---- layer 3 (OUT = 64, straight to d_out) ----
    gemm_reg_k<64, true><<<dim3(gemm_grid), blk, 0, stream>>>(bufB, wt3, scale, shift,
                                                              dis, Hs, N);
    gather_k<64, false><<<dim3(NBg * 2), blk, 0, stream>>>(Hs, dis, b3, row_ptr, esrc,
                                                           out, nullptr, nullptr, N);
}

// Round 11
// 429.771 us; speedup vs baseline: 1.6495x; 1.0551x over previous
//
#include <hip/hip_runtime.h>
#include <hip/hip_fp16.h>

// ---------------------------------------------------------------------------
// GCN 3-layer forward:  (GCNConv -> BN) x2 -> GCNConv
// N=100000, E=1600000, IN=H=128, OUT=64
// Round 10: gather with 4 lanes/64B-row (halved VGPR -> higher occupancy,
//           same 8-deep load pipeline), f16 inter-layer buffer (bufB),
//           f16 A-fragment GEMM for layers 2-3. Build pipeline unchanged.
// ---------------------------------------------------------------------------

constexpr int BSH = 7;            // 128 nodes per bucket
constexpr int NXCD = 8;

typedef _Float16 half8 __attribute__((ext_vector_type(8)));
typedef float f32x4 __attribute__((ext_vector_type(4)));

static __device__ inline ushort f2h(float f) {
    union { __half h; ushort u; } cv;
    cv.h = __float2half_rn(f);
    return cv.u;
}
static __device__ inline float2 h2f2(unsigned int u) {
    union { unsigned int u; __half2 h; } cv;
    cv.u = u;
    return __half22float2(cv.h);
}

// accumulate 8 f16 (one uint4) into acc[0..8)
#define ACC8(v) do { float2 _f; \
    _f = h2f2((v).x); acc[0] += _f.x; acc[1] += _f.y; \
    _f = h2f2((v).y); acc[2] += _f.x; acc[3] += _f.y; \
    _f = h2f2((v).z); acc[4] += _f.x; acc[5] += _f.y; \
    _f = h2f2((v).w); acc[6] += _f.x; acc[7] += _f.y; \
} while (0)

// ---- phase A: per-xcd bucket histogram (LDS-aggregated) -------------------
__global__ __launch_bounds__(256) void count_k(const int* __restrict__ dst,
                                               int* __restrict__ hist,
                                               int E, int EPB, int nbuk) {
    __shared__ int lh[1024];
    for (int i = threadIdx.x; i < nbuk; i += 256) lh[i] = 0;
    __syncthreads();
    const int e0 = blockIdx.x * EPB;
    const int e1 = min(e0 + EPB, E);
    for (int e = e0 + threadIdx.x; e < e1; e += 256)
        atomicAdd(&lh[dst[e] >> BSH], 1);
    __syncthreads();
    const int xcd = blockIdx.x & (NXCD - 1);
    for (int i = threadIdx.x; i < nbuk; i += 256) {
        int v = lh[i];
        if (v) atomicAdd(&hist[xcd * nbuk + i], v);
    }
}

// ---- phase B: scan hist (key order: bucket-major, xcd-minor) --------------
// Also zeroes the BN stats accumulators (sums|sumsq = stats[0..255]).
__global__ __launch_bounds__(256) void scan_hist_k(const int* __restrict__ hist,
                                                   int* __restrict__ cur,
                                                   int* __restrict__ bstart,
                                                   int* __restrict__ row_ptr,
                                                   float* __restrict__ stats,
                                                   int nbuk, int n, int E) {
    stats[threadIdx.x] = 0.f;            // 256 threads cover sums+sumsq
    const int NT = nbuk * NXCD;          // <= 8192 assumed
    const int C = (NT + 255) / 256;      // <= 32
    int vals[32];
    const int tid = threadIdx.x;
    int sum = 0;
#pragma unroll
    for (int k = 0; k < 32; ++k) {
        if (k >= C) break;
        int key = tid * C + k;
        int v = 0;
        if (key < NT) {
            int b = key >> 3, x = key & 7;
            v = hist[x * nbuk + b];
        }
        vals[k] = v;
        sum += v;
    }
    __shared__ int part[256];
    part[tid] = sum;
    __syncthreads();
    for (int off = 1; off < 256; off <<= 1) {
        int t = 0;
        if (tid >= off) t = part[tid - off];
        __syncthreads();
        part[tid] += t;
        __syncthreads();
    }
    int run = (tid == 0) ? 0 : part[tid - 1];
#pragma unroll
    for (int k = 0; k < 32; ++k) {
        if (k >= C) break;
        int key = tid * C + k;
        if (key < NT) {
            int b = key >> 3, x = key & 7;
            cur[x * nbuk + b] = run;
            if (x == 0) bstart[b] = run;
        }
        run += vals[k];
    }
    if (tid == 0) { bstart[nbuk] = E; row_ptr[n] = E; }
}

// ---- phase C: two-pass LDS-aggregated scatter into (bucket, xcd) segments -
__global__ __launch_bounds__(256) void scatter_bucket_k(const int* __restrict__ src,
                                                        const int* __restrict__ dst,
                                                        int* __restrict__ cur,
                                                        unsigned int* __restrict__ ebuf,
                                                        int E, int EPB, int nbuk) {
    __shared__ int lh[1024];
    __shared__ int base[1024];
    for (int i = threadIdx.x; i < nbuk; i += 256) lh[i] = 0;
    __syncthreads();
    const int e0 = blockIdx.x * EPB;
    const int e1 = min(e0 + EPB, E);
    const int xcd = blockIdx.x & (NXCD - 1);
    for (int e = e0 + threadIdx.x; e < e1; e += 256)
        atomicAdd(&lh[dst[e] >> BSH], 1);
    __syncthreads();
    for (int i = threadIdx.x; i < nbuk; i += 256) {
        int v = lh[i];
        base[i] = v ? atomicAdd(&cur[xcd * nbuk + i], v) : 0;
        lh[i] = 0;                      // becomes cursor
    }
    __syncthreads();
    for (int e = e0 + threadIdx.x; e < e1; e += 256) {
        int d = dst[e];
        int s = src[e];
        int b = d >> BSH;
        int pos = base[b] + atomicAdd(&lh[b], 1);
        ebuf[pos] = ((unsigned int)s << BSH) | (unsigned int)(d & 127);
    }
}

// ---- phase D: per-bucket LDS counting sort -> per-node esrc + row_ptr -----
__global__ __launch_bounds__(256) void bucket_sort_k(const unsigned int* __restrict__ ebuf,
                                                     const int* __restrict__ bstart,
                                                     int* __restrict__ row_ptr,
                                                     int* __restrict__ esrc, int n) {
    const int b = blockIdx.x;
    const int beg = bstart[b];
    const int end = bstart[b + 1];
    __shared__ int cnt[128], off[128];
    if (threadIdx.x < 128) cnt[threadIdx.x] = 0;
    __syncthreads();
    for (int i = beg + threadIdx.x; i < end; i += 256)
        atomicAdd(&cnt[ebuf[i] & 127], 1);
    __syncthreads();
    if (threadIdx.x < 128) off[threadIdx.x] = cnt[threadIdx.x];
    __syncthreads();
    for (int d = 1; d < 128; d <<= 1) {
        int t = 0;
        if (threadIdx.x < 128 && threadIdx.x >= d) t = off[threadIdx.x - d];
        __syncthreads();
        if (threadIdx.x < 128) off[threadIdx.x] += t;
        __syncthreads();
    }
    if (threadIdx.x < 128) {
        int ex = off[threadIdx.x] - cnt[threadIdx.x];   // exclusive
        int node = (b << BSH) + threadIdx.x;
        if (node < n) row_ptr[node] = beg + ex;
        cnt[threadIdx.x] = ex;                          // reuse as cursor
    }
    __syncthreads();
    for (int i = beg + threadIdx.x; i < end; i += 256) {
        unsigned int p = ebuf[i];
        int l = (int)(p & 127);
        int pos = beg + atomicAdd(&cnt[l], 1);
        esrc[pos] = (int)(p >> BSH);
    }
}

// ---- dis from row_ptr diffs ----------------------------------------------
__global__ void rowptr_to_dis_k(const int* __restrict__ row_ptr,
                                float* __restrict__ dis, int n) {
    int i = blockIdx.x * blockDim.x + threadIdx.x;
    if (i < n) {
        int deg = row_ptr[i + 1] - row_ptr[i];
        dis[i] = rsqrtf((float)deg + 1.0f);   // +1 self loop
    }
}

// ---- W^T f16 prep: WT[n][k] = f16(W[k][n]), once per launch ---------------
__global__ __launch_bounds__(256) void prep_wt_k(const float* __restrict__ W1,
                                                 const float* __restrict__ W2,
                                                 const float* __restrict__ W3,
                                                 ushort* __restrict__ wt1,
                                                 ushort* __restrict__ wt2,
                                                 ushort* __restrict__ wt3) {
    const float* W; ushort* WT; int OUTD;
    if (blockIdx.x == 0)      { W = W1; WT = wt1; OUTD = 128; }
    else if (blockIdx.x == 1) { W = W2; WT = wt2; OUTD = 128; }
    else                      { W = W3; WT = wt3; OUTD = 64; }
    const int tot = 128 * OUTD;
    for (int idx = threadIdx.x; idx < tot; idx += 256) {
        int nq = idx >> 7;          // output col
        int k  = idx & 127;         // input k
        WT[idx] = f2h(W[k * OUTD + nq]);
    }
}

// ------- register MFMA GEMM: Hs = f16( (BN(X) @ W) * dis ) -----------------
// Zero LDS. Block = 4 waves x 16 rows = 64 rows. A from global X (f32 or f16,
// BN fused); B from f16 W^T (L1-resident).
// Hs layout: [NCHUNK][N][32 f16], chunk c holds columns [32c, 32c+32).
template <int OUTD, bool XF16, bool BNIN>
__global__ __launch_bounds__(256) void gemm_reg_k(const void* __restrict__ Xv,
                                                  const ushort* __restrict__ WT,
                                                  const float* __restrict__ scale,
                                                  const float* __restrict__ shift,
                                                  const float* __restrict__ dis,
                                                  ushort* __restrict__ Hs, int nn) {
    constexpr int NCT = OUTD / 16;       // col tiles: 8 or 4
    const int wave = threadIdx.x >> 6;
    const int lane = threadIdx.x & 63;
    const int l15 = lane & 15;
    const int kg = lane >> 4;            // 0..3
    const int row = blockIdx.x * 64 + wave * 16 + l15;

    // A fragments: row fixed, k = kk*32 + kg*8 + [0..8)
    half8 a[4];
#pragma unroll
    for (int kk = 0; kk < 4; ++kk) {
        float v[8];
        if (row < nn) {
            if (XF16) {
                const uint4* xp = (const uint4*)((const ushort*)Xv + (size_t)row * 128
                                                 + kk * 32 + kg * 8);
                uint4 raw = *xp;
                float2 f;
                f = h2f2(raw.x); v[0] = f.x; v[1] = f.y;
                f = h2f2(raw.y); v[2] = f.x; v[3] = f.y;
                f = h2f2(raw.z); v[4] = f.x; v[5] = f.y;
                f = h2f2(raw.w); v[6] = f.x; v[7] = f.y;
            } else {
                const float4* xp = (const float4*)((const float*)Xv + (size_t)row * 128
                                                   + kk * 32 + kg * 8);
                float4 v0 = xp[0];
                float4 v1 = xp[1];
                v[0] = v0.x; v[1] = v0.y; v[2] = v0.z; v[3] = v0.w;
                v[4] = v1.x; v[5] = v1.y; v[6] = v1.z; v[7] = v1.w;
            }
            if (BNIN) {
                int kq = kk * 8 + kg * 2;
                float4 s0 = ((const float4*)scale)[kq];
                float4 s1 = ((const float4*)scale)[kq + 1];
                float4 h0 = ((const float4*)shift)[kq];
                float4 h1 = ((const float4*)shift)[kq + 1];
                v[0] = v[0] * s0.x + h0.x;
                v[1] = v[1] * s0.y + h0.y;
                v[2] = v[2] * s0.z + h0.z;
                v[3] = v[3] * s0.w + h0.w;
                v[4] = v[4] * s1.x + h1.x;
                v[5] = v[5] * s1.y + h1.y;
                v[6] = v[6] * s1.z + h1.z;
                v[7] = v[7] * s1.w + h1.w;
            }
#pragma unroll
            for (int j = 0; j < 8; ++j) a[kk][j] = (_Float16)v[j];
        } else {
#pragma unroll
            for (int j = 0; j < 8; ++j) a[kk][j] = (_Float16)0.f;
        }
    }

    f32x4 acc[NCT];
#pragma unroll
    for (int ct = 0; ct < NCT; ++ct) acc[ct] = (f32x4){0.f, 0.f, 0.f, 0.f};

#pragma unroll
    for (int kk = 0; kk < 4; ++kk) {
#pragma unroll
        for (int ct = 0; ct < NCT; ++ct) {
            half8 bfr = *(const half8*)&WT[(ct * 16 + l15) * 128 + kk * 32 + kg * 8];
            acc[ct] = __builtin_amdgcn_mfma_f32_16x16x32_f16(a[kk], bfr, acc[ct], 0, 0, 0);
        }
    }

    // D: col = lane&15 (within ct), row = kg*4 + reg (within wave tile)
    const int mbase = blockIdx.x * 64 + wave * 16 + kg * 4;
    float dm[4];
#pragma unroll
    for (int reg = 0; reg < 4; ++reg) {
        int m = mbase + reg;
        dm[reg] = (m < nn) ? dis[m] : 0.f;
    }
#pragma unroll
    for (int ct = 0; ct < NCT; ++ct) {
        int ncol = ct * 16 + l15;
        size_t cb = (size_t)(ncol >> 5) * nn * 32 + (ncol & 31);
#pragma unroll
        for (int reg = 0; reg < 4; ++reg) {
            int m = mbase + reg;
            if (m < nn) Hs[cb + (size_t)m * 32] = f2h(acc[ct][reg] * dm[reg]);
        }
    }
}

// ---------------- chunked gather aggregation (+ fused BN stats) ------------
// Per chunk c (32 cols): O[i][32c..32c+32) = dis[i]*(Hs_c[i] + sum Hs_c[src]) + b
// 4 lanes per 64B row (1 uint4 each); unroll-8 pipeline (8 loads in flight).
// OUTF16: write f16 (inter-layer buffer); else f32 (final output).
template <int OUTD, bool STATS, bool OUTF16>
__global__ __launch_bounds__(256) void gather_k(const ushort* __restrict__ Hs,
                                                const float* __restrict__ dis,
                                                const float* __restrict__ b,
                                                const int* __restrict__ row_ptr,
                                                const int* __restrict__ esrc,
                                                void* __restrict__ Ov,
                                                float* __restrict__ sums,
                                                float* __restrict__ sumsq, int n) {
    constexpr int NCHUNK = OUTD / 32;   // 4 or 2

    __shared__ float s_sum[32];
    __shared__ float s_sq[32];
    if (STATS) {
        if (threadIdx.x < 32) { s_sum[threadIdx.x] = 0.f; s_sq[threadIdx.x] = 0.f; }
        __syncthreads();
    }

    const int chunk = blockIdx.x & (NCHUNK - 1);
    const int nblk  = blockIdx.x / NCHUNK;
    const int g     = threadIdx.x >> 2;     // node within block: 0..63
    const int lane  = threadIdx.x & 3;      // uint4 within the 64B row
    const int node  = nblk * 64 + g;

    float acc[8];
#pragma unroll
    for (int c = 0; c < 8; ++c) acc[c] = 0.f;
    float o[8];
#pragma unroll
    for (int c = 0; c < 8; ++c) o[c] = 0.f;

    if (node < n) {
        const uint4* Hc = (const uint4*)Hs + (size_t)chunk * n * 4;  // 4 uint4/node

        {   // self row (dis pre-folded into Hs)
            uint4 v = Hc[(size_t)node * 4 + lane];
            ACC8(v);
        }
        const int beg = row_ptr[node];
        const int end = row_ptr[node + 1];
        int j = beg;
        const int end8 = beg + ((end - beg) & ~7);
        for (; j < end8; j += 8) {
            int s[8];
#pragma unroll
            for (int u = 0; u < 8; ++u) s[u] = esrc[j + u];
            uint4 va[8];
#pragma unroll
            for (int u = 0; u < 8; ++u) va[u] = Hc[(size_t)s[u] * 4 + lane];
#pragma unroll
            for (int u = 0; u < 8; ++u) { ACC8(va[u]); }
        }
        for (; j < end; ++j) {
            int s = esrc[j];
            uint4 a = Hc[(size_t)s * 4 + lane];
            ACC8(a);
        }

        float dd = dis[node];
        const float4* B4 = (const float4*)b + chunk * 8 + lane * 2;
        float4 b0 = B4[0];
        float4 b1 = B4[1];
        o[0] = acc[0] * dd + b0.x;
        o[1] = acc[1] * dd + b0.y;
        o[2] = acc[2] * dd + b0.z;
        o[3] = acc[3] * dd + b0.w;
        o[4] = acc[4] * dd + b1.x;
        o[5] = acc[5] * dd + b1.y;
        o[6] = acc[6] * dd + b1.z;
        o[7] = acc[7] * dd + b1.w;

        if (OUTF16) {
            union { ushort us[8]; uint4 v; } pk;
#pragma unroll
            for (int c = 0; c < 8; ++c) pk.us[c] = f2h(o[c]);
            ((uint4*)Ov)[(size_t)node * (OUTD / 8) + chunk * 4 + lane] = pk.v;
        } else {
            float4* O4 = (float4*)Ov + (size_t)node * (OUTD / 4) + chunk * 8 + lane * 2;
            O4[0] = make_float4(o[0], o[1], o[2], o[3]);
            O4[1] = make_float4(o[4], o[5], o[6], o[7]);
        }
    }

    if (STATS) {
        // 16 lanes of a wave with equal (lane&3) hold the same 8 columns
        float sv[8], qv[8];
#pragma unroll
        for (int c = 0; c < 8; ++c) { sv[c] = o[c]; qv[c] = o[c] * o[c]; }
#pragma unroll
        for (int c = 0; c < 8; ++c) {
#pragma unroll
            for (int m = 4; m <= 32; m <<= 1) {
                sv[c] += __shfl_xor(sv[c], m);
                qv[c] += __shfl_xor(qv[c], m);
            }
        }
        if ((threadIdx.x & 63) < 4) {
            int c0 = lane * 8;
#pragma unroll
            for (int c = 0; c < 8; ++c) {
                atomicAdd(&s_sum[c0 + c], sv[c]);
                atomicAdd(&s_sq[c0 + c], qv[c]);
            }
        }
        __syncthreads();
        if (threadIdx.x < 32) {
            atomicAdd(&sums[chunk * 32 + threadIdx.x], s_sum[threadIdx.x]);
            atomicAdd(&sumsq[chunk * 32 + threadIdx.x], s_sq[threadIdx.x]);
        }
    }
}

// ---- BN finalize: scale/shift from sums; self-zeroes stats for next layer -
__global__ void bn_finalize_k(float* __restrict__ sums, float* __restrict__ sumsq,
                              const float* __restrict__ g, const float* __restrict__ be,
                              float* __restrict__ scale, float* __restrict__ shift, int n) {
    int c = threadIdx.x;  // 128 threads
    float inv_n = 1.0f / (float)n;
    float m = sums[c] * inv_n;
    float v = sumsq[c] * inv_n - m * m;
    float sc = rsqrtf(v + 1e-5f) * g[c];
    scale[c] = sc;
    shift[c] = be[c] - m * sc;
    sums[c] = 0.f;
    sumsq[c] = 0.f;
}

// ---------------------------------------------------------------------------
extern "C" void kernel_launch(void* const* d_in, const int* in_sizes, int n_in,
                              void* d_out, int out_size, void* d_ws, size_t ws_size,
                              hipStream_t stream) {
    const float* x   = (const float*)d_in[0];
    const int*   ei  = (const int*)d_in[1];
    const float* W1  = (const float*)d_in[2];
    const float* b1  = (const float*)d_in[3];
    const float* g1  = (const float*)d_in[4];
    const float* be1 = (const float*)d_in[5];
    const float* W2  = (const float*)d_in[6];
    const float* b2  = (const float*)d_in[7];
    const float* g2  = (const float*)d_in[8];
    const float* be2 = (const float*)d_in[9];
    const float* W3  = (const float*)d_in[10];
    const float* b3  = (const float*)d_in[11];
    float* out = (float*)d_out;

    const int N = in_sizes[0] / 128;
    const int E = in_sizes[1] / 2;
    const int* src = ei;
    const int* dst = ei + E;
    const int NBUK = (N + 127) >> BSH;

    // ---- workspace layout ----
    float* wsp   = (float*)d_ws;
    float* dis   = wsp;                               // N f32
    float* stats = wsp + N;                           // 512 f32
    ushort* wt1  = (ushort*)(stats + 512);            // 128*128 f16
    ushort* wt2  = wt1 + 128 * 128;
    ushort* wt3  = wt2 + 128 * 128;                   // 128*64 f16
    int*   hist   = (int*)(wt3 + 128 * 64);           // NBUK*8
    int*   cur    = hist + NBUK * NXCD;               // NBUK*8
    int*   bstart = cur + NBUK * NXCD;                // NBUK+1
    int*   row_ptr = bstart + NBUK + 1 + 63;          // N+1
    float* bufA  = (float*)((((uintptr_t)(row_ptr + N + 1)) + 255) & ~(uintptr_t)255);
    float* bufB  = bufA + (size_t)N * 128;            // N*128 region (f16 used)
    unsigned int* ebuf = (unsigned int*)(bufB + (size_t)N * 128);  // E u32
    int*   esrc  = (int*)(ebuf + E);                  // E int

    ushort* Hs  = (ushort*)bufA;                      // [NCHUNK][N][32] f16
    ushort* Bf16 = (ushort*)bufB;                     // [N][128] f16 inter-layer

    float* sums  = stats;
    float* sumsq = stats + 128;
    float* scale = stats + 256;
    float* shift = stats + 384;

    const int BS = 256;
    dim3 blk(BS);
    const int NB = (N + 255) / 256;
    const int SGRID = 128;                 // count/scatter blocks (multiple of 8)
    const int EPB = (E + SGRID - 1) / SGRID;

    // ---- bucket-sorted CSR build ----
    hipMemsetAsync(hist, 0, (size_t)NBUK * NXCD * 4, stream);
    prep_wt_k<<<dim3(3), blk, 0, stream>>>(W1, W2, W3, wt1, wt2, wt3);
    count_k<<<dim3(SGRID), blk, 0, stream>>>(dst, hist, E, EPB, NBUK);
    scan_hist_k<<<dim3(1), blk, 0, stream>>>(hist, cur, bstart, row_ptr, stats, NBUK, N, E);
    scatter_bucket_k<<<dim3(SGRID), blk, 0, stream>>>(src, dst, cur, ebuf, E, EPB, NBUK);
    bucket_sort_k<<<dim3(NBUK), blk, 0, stream>>>(ebuf, bstart, row_ptr, esrc, N);
    rowptr_to_dis_k<<<dim3(NB), blk, 0, stream>>>(row_ptr, dis, N);

    const int gemm_grid = (N + 63) / 64;
    const int NBg = (N + 63) / 64;      // gather node-blocks (64 nodes/block)

    // ---- layer 1 ----
    gemm_reg_k<128, false, false><<<dim3(gemm_grid), blk, 0, stream>>>(
        x, wt1, nullptr, nullptr, dis, Hs, N);
    gather_k<128, true, true><<<dim3(NBg * 4), blk, 0, stream>>>(
        Hs, dis, b1, row_ptr, esrc, Bf16, sums, sumsq, N);
    bn_finalize_k<<<dim3(1), dim3(128), 0, stream>>>(sums, sumsq, g1, be1, scale, shift, N);

    // ---- layer 2 (BN applied inside GEMM A-fragment load, f16 input) ----
    gemm_reg_k<128, true, true><<<dim3(gemm_grid), blk, 0, stream>>>(
        Bf16, wt2, scale, shift, dis, Hs, N);
    gather_k<128, true, true><<<dim3(NBg * 4), blk, 0, stream>>>(
        Hs, dis, b2, row_ptr, esrc, Bf16, sums, sumsq, N);
    bn_finalize_k<<<dim3(1), dim3(128), 0, stream>>>(sums, sumsq, g2, be2, scale, shift, N);

    // ---- layer 3 (OUT = 64, f32 straight to d_out) ----
    gemm_reg_k<64, true, true><<<dim3(gemm_grid), blk, 0, stream>>>(
        Bf16, wt3, scale, shift, dis, Hs, N);
    gather_k<64, false, false><<<dim3(NBg * 2), blk, 0, stream>>>(
        Hs, dis, b3, row_ptr, esrc, out, nullptr, nullptr, N);
}

// Round 12
// 405.065 us; speedup vs baseline: 1.7501x; 1.0610x over previous
//
#include <hip/hip_runtime.h>
#include <hip/hip_fp16.h>

// ---------------------------------------------------------------------------
// GCN 3-layer forward:  (GCNConv -> BN) x2 -> GCNConv
// N=100000, E=1600000, IN=H=128, OUT=64
// Round 11: packed-f16 (v_pk_add_f16) gather accumulation (4x less VALU
//           between load batches), BN finalize fused into GEMM blocks
//           (double-banked stats), prep_wt/dis folded into build kernels.
// ---------------------------------------------------------------------------

constexpr int BSH = 7;            // 128 nodes per bucket
constexpr int NXCD = 8;

typedef _Float16 half8 __attribute__((ext_vector_type(8)));
typedef float f32x4 __attribute__((ext_vector_type(4)));

static __device__ inline ushort f2h(float f) {
    union { __half h; ushort u; } cv;
    cv.h = __float2half_rn(f);
    return cv.u;
}
static __device__ inline float2 h2f2(unsigned int u) {
    union { unsigned int u; __half2 h; } cv;
    cv.u = u;
    return __half22float2(cv.h);
}
static __device__ inline __half2 u2h2(unsigned int u) {
    union { unsigned int u; __half2 h; } cv;
    cv.u = u;
    return cv.h;
}

// packed-f16 accumulate: one uint4 (8 f16) into 4 half2 accumulators
#define ACCPK(v) do { \
    acch[0] = __hadd2(acch[0], u2h2((v).x)); \
    acch[1] = __hadd2(acch[1], u2h2((v).y)); \
    acch[2] = __hadd2(acch[2], u2h2((v).z)); \
    acch[3] = __hadd2(acch[3], u2h2((v).w)); \
} while (0)

// ---- phase A: per-xcd bucket histogram + W^T f16 prep (blocks 0-2) --------
__global__ __launch_bounds__(256) void countwt_k(const int* __restrict__ dst,
                                                 int* __restrict__ hist,
                                                 int E, int EPB, int nbuk,
                                                 const float* __restrict__ W1,
                                                 const float* __restrict__ W2,
                                                 const float* __restrict__ W3,
                                                 ushort* __restrict__ wt1,
                                                 ushort* __restrict__ wt2,
                                                 ushort* __restrict__ wt3) {
    if (blockIdx.x < 3) {
        const float* W; ushort* WT; int OUTD;
        if (blockIdx.x == 0)      { W = W1; WT = wt1; OUTD = 128; }
        else if (blockIdx.x == 1) { W = W2; WT = wt2; OUTD = 128; }
        else                      { W = W3; WT = wt3; OUTD = 64; }
        const int tot = 128 * OUTD;
        for (int idx = threadIdx.x; idx < tot; idx += 256) {
            int nq = idx >> 7;          // output col
            int k  = idx & 127;         // input k
            WT[idx] = f2h(W[k * OUTD + nq]);
        }
        return;
    }
    const int bid = blockIdx.x - 3;
    __shared__ int lh[1024];
    for (int i = threadIdx.x; i < nbuk; i += 256) lh[i] = 0;
    __syncthreads();
    const int e0 = bid * EPB;
    const int e1 = min(e0 + EPB, E);
    for (int e = e0 + threadIdx.x; e < e1; e += 256)
        atomicAdd(&lh[dst[e] >> BSH], 1);
    __syncthreads();
    const int xcd = bid & (NXCD - 1);
    for (int i = threadIdx.x; i < nbuk; i += 256) {
        int v = lh[i];
        if (v) atomicAdd(&hist[xcd * nbuk + i], v);
    }
}

// ---- phase B: scan hist; zero BOTH BN stats banks (stats[0..511]) ---------
__global__ __launch_bounds__(256) void scan_hist_k(const int* __restrict__ hist,
                                                   int* __restrict__ cur,
                                                   int* __restrict__ bstart,
                                                   int* __restrict__ row_ptr,
                                                   float* __restrict__ stats,
                                                   int nbuk, int n, int E) {
    stats[threadIdx.x] = 0.f;
    stats[threadIdx.x + 256] = 0.f;
    const int NT = nbuk * NXCD;          // <= 8192 assumed
    const int C = (NT + 255) / 256;      // <= 32
    int vals[32];
    const int tid = threadIdx.x;
    int sum = 0;
#pragma unroll
    for (int k = 0; k < 32; ++k) {
        if (k >= C) break;
        int key = tid * C + k;
        int v = 0;
        if (key < NT) {
            int b = key >> 3, x = key & 7;
            v = hist[x * nbuk + b];
        }
        vals[k] = v;
        sum += v;
    }
    __shared__ int part[256];
    part[tid] = sum;
    __syncthreads();
    for (int off = 1; off < 256; off <<= 1) {
        int t = 0;
        if (tid >= off) t = part[tid - off];
        __syncthreads();
        part[tid] += t;
        __syncthreads();
    }
    int run = (tid == 0) ? 0 : part[tid - 1];
#pragma unroll
    for (int k = 0; k < 32; ++k) {
        if (k >= C) break;
        int key = tid * C + k;
        if (key < NT) {
            int b = key >> 3, x = key & 7;
            cur[x * nbuk + b] = run;
            if (x == 0) bstart[b] = run;
        }
        run += vals[k];
    }
    if (tid == 0) { bstart[nbuk] = E; row_ptr[n] = E; }
}

// ---- phase C: two-pass LDS-aggregated scatter into (bucket, xcd) segments -
__global__ __launch_bounds__(256) void scatter_bucket_k(const int* __restrict__ src,
                                                        const int* __restrict__ dst,
                                                        int* __restrict__ cur,
                                                        unsigned int* __restrict__ ebuf,
                                                        int E, int EPB, int nbuk) {
    __shared__ int lh[1024];
    __shared__ int base[1024];
    for (int i = threadIdx.x; i < nbuk; i += 256) lh[i] = 0;
    __syncthreads();
    const int e0 = blockIdx.x * EPB;
    const int e1 = min(e0 + EPB, E);
    const int xcd = blockIdx.x & (NXCD - 1);
    for (int e = e0 + threadIdx.x; e < e1; e += 256)
        atomicAdd(&lh[dst[e] >> BSH], 1);
    __syncthreads();
    for (int i = threadIdx.x; i < nbuk; i += 256) {
        int v = lh[i];
        base[i] = v ? atomicAdd(&cur[xcd * nbuk + i], v) : 0;
        lh[i] = 0;                      // becomes cursor
    }
    __syncthreads();
    for (int e = e0 + threadIdx.x; e < e1; e += 256) {
        int d = dst[e];
        int s = src[e];
        int b = d >> BSH;
        int pos = base[b] + atomicAdd(&lh[b], 1);
        ebuf[pos] = ((unsigned int)s << BSH) | (unsigned int)(d & 127);
    }
}

// ---- phase D: per-bucket counting sort -> esrc + row_ptr + dis ------------
__global__ __launch_bounds__(256) void bucket_sort_k(const unsigned int* __restrict__ ebuf,
                                                     const int* __restrict__ bstart,
                                                     int* __restrict__ row_ptr,
                                                     int* __restrict__ esrc,
                                                     float* __restrict__ dis, int n) {
    const int b = blockIdx.x;
    const int beg = bstart[b];
    const int end = bstart[b + 1];
    __shared__ int cnt[128], off[128];
    if (threadIdx.x < 128) cnt[threadIdx.x] = 0;
    __syncthreads();
    for (int i = beg + threadIdx.x; i < end; i += 256)
        atomicAdd(&cnt[ebuf[i] & 127], 1);
    __syncthreads();
    if (threadIdx.x < 128) off[threadIdx.x] = cnt[threadIdx.x];
    __syncthreads();
    for (int d = 1; d < 128; d <<= 1) {
        int t = 0;
        if (threadIdx.x < 128 && threadIdx.x >= d) t = off[threadIdx.x - d];
        __syncthreads();
        if (threadIdx.x < 128) off[threadIdx.x] += t;
        __syncthreads();
    }
    if (threadIdx.x < 128) {
        int deg = cnt[threadIdx.x];
        int ex = off[threadIdx.x] - deg;                // exclusive
        int node = (b << BSH) + threadIdx.x;
        if (node < n) {
            row_ptr[node] = beg + ex;
            dis[node] = rsqrtf((float)deg + 1.0f);      // +1 self loop
        }
        cnt[threadIdx.x] = ex;                          // reuse as cursor
    }
    __syncthreads();
    for (int i = beg + threadIdx.x; i < end; i += 256) {
        unsigned int p = ebuf[i];
        int l = (int)(p & 127);
        int pos = beg + atomicAdd(&cnt[l], 1);
        esrc[pos] = (int)(p >> BSH);
    }
}

// ------- register MFMA GEMM: Hs = f16( (BN(X) @ W) * dis ) -----------------
// Zero-LDS main path. Block = 4 waves x 16 rows = 64 rows. A from global X
// (f32 or f16); B from f16 W^T (L1-resident). When BNIN, each block computes
// BN scale/shift from the raw stats bank (sums|sumsq) + (g,be) into LDS.
// Hs layout: [NCHUNK][N][32 f16], chunk c holds columns [32c, 32c+32).
template <int OUTD, bool XF16, bool BNIN>
__global__ __launch_bounds__(256) void gemm_reg_k(const void* __restrict__ Xv,
                                                  const ushort* __restrict__ WT,
                                                  const float* __restrict__ sums,
                                                  const float* __restrict__ gg,
                                                  const float* __restrict__ be,
                                                  const float* __restrict__ dis,
                                                  ushort* __restrict__ Hs, int nn) {
    constexpr int NCT = OUTD / 16;       // col tiles: 8 or 4
    __shared__ __align__(16) float s_scale[BNIN ? 128 : 4];
    __shared__ __align__(16) float s_shift[BNIN ? 128 : 4];
    if (BNIN) {
        if (threadIdx.x < 128) {
            int c = threadIdx.x;
            float inv_n = 1.0f / (float)nn;
            float m = sums[c] * inv_n;
            float v = sums[c + 128] * inv_n - m * m;
            float sc = rsqrtf(v + 1e-5f) * gg[c];
            s_scale[c] = sc;
            s_shift[c] = be[c] - m * sc;
        }
        __syncthreads();
    }

    const int wave = threadIdx.x >> 6;
    const int lane = threadIdx.x & 63;
    const int l15 = lane & 15;
    const int kg = lane >> 4;            // 0..3
    const int row = blockIdx.x * 64 + wave * 16 + l15;

    // A fragments: row fixed, k = kk*32 + kg*8 + [0..8)
    half8 a[4];
#pragma unroll
    for (int kk = 0; kk < 4; ++kk) {
        float v[8];
        if (row < nn) {
            if (XF16) {
                const uint4* xp = (const uint4*)((const ushort*)Xv + (size_t)row * 128
                                                 + kk * 32 + kg * 8);
                uint4 raw = *xp;
                float2 f;
                f = h2f2(raw.x); v[0] = f.x; v[1] = f.y;
                f = h2f2(raw.y); v[2] = f.x; v[3] = f.y;
                f = h2f2(raw.z); v[4] = f.x; v[5] = f.y;
                f = h2f2(raw.w); v[6] = f.x; v[7] = f.y;
            } else {
                const float4* xp = (const float4*)((const float*)Xv + (size_t)row * 128
                                                   + kk * 32 + kg * 8);
                float4 v0 = xp[0];
                float4 v1 = xp[1];
                v[0] = v0.x; v[1] = v0.y; v[2] = v0.z; v[3] = v0.w;
                v[4] = v1.x; v[5] = v1.y; v[6] = v1.z; v[7] = v1.w;
            }
            if (BNIN) {
                int kq = kk * 8 + kg * 2;
                float4 s0 = ((const float4*)s_scale)[kq];
                float4 s1 = ((const float4*)s_scale)[kq + 1];
                float4 h0 = ((const float4*)s_shift)[kq];
                float4 h1 = ((const float4*)s_shift)[kq + 1];
                v[0] = v[0] * s0.x + h0.x;
                v[1] = v[1] * s0.y + h0.y;
                v[2] = v[2] * s0.z + h0.z;
                v[3] = v[3] * s0.w + h0.w;
                v[4] = v[4] * s1.x + h1.x;
                v[5] = v[5] * s1.y + h1.y;
                v[6] = v[6] * s1.z + h1.z;
                v[7] = v[7] * s1.w + h1.w;
            }
#pragma unroll
            for (int j = 0; j < 8; ++j) a[kk][j] = (_Float16)v[j];
        } else {
#pragma unroll
            for (int j = 0; j < 8; ++j) a[kk][j] = (_Float16)0.f;
        }
    }

    f32x4 acc[NCT];
#pragma unroll
    for (int ct = 0; ct < NCT; ++ct) acc[ct] = (f32x4){0.f, 0.f, 0.f, 0.f};

#pragma unroll
    for (int kk = 0; kk < 4; ++kk) {
#pragma unroll
        for (int ct = 0; ct < NCT; ++ct) {
            half8 bfr = *(const half8*)&WT[(ct * 16 + l15) * 128 + kk * 32 + kg * 8];
            acc[ct] = __builtin_amdgcn_mfma_f32_16x16x32_f16(a[kk], bfr, acc[ct], 0, 0, 0);
        }
    }

    // D: col = lane&15 (within ct), row = kg*4 + reg (within wave tile)
    const int mbase = blockIdx.x * 64 + wave * 16 + kg * 4;
    float dm[4];
#pragma unroll
    for (int reg = 0; reg < 4; ++reg) {
        int m = mbase + reg;
        dm[reg] = (m < nn) ? dis[m] : 0.f;
    }
#pragma unroll
    for (int ct = 0; ct < NCT; ++ct) {
        int ncol = ct * 16 + l15;
        size_t cb = (size_t)(ncol >> 5) * nn * 32 + (ncol & 31);
#pragma unroll
        for (int reg = 0; reg < 4; ++reg) {
            int m = mbase + reg;
            if (m < nn) Hs[cb + (size_t)m * 32] = f2h(acc[ct][reg] * dm[reg]);
        }
    }
}

// ---------------- chunked gather aggregation (+ fused BN stats) ------------
// Per chunk c (32 cols): O[i][32c..32c+32) = dis[i]*(Hs_c[i] + sum Hs_c[src]) + b
// 4 lanes per 64B row; unroll-8 pipeline; packed-f16 accumulation
// (v_pk_add_f16, 4 VALU/uint4 instead of 16) -> faster load-batch turnaround.
template <int OUTD, bool STATS, bool OUTF16>
__global__ __launch_bounds__(256) void gather_k(const ushort* __restrict__ Hs,
                                                const float* __restrict__ dis,
                                                const float* __restrict__ b,
                                                const int* __restrict__ row_ptr,
                                                const int* __restrict__ esrc,
                                                void* __restrict__ Ov,
                                                float* __restrict__ sums,
                                                float* __restrict__ sumsq, int n) {
    constexpr int NCHUNK = OUTD / 32;   // 4 or 2

    __shared__ float s_sum[32];
    __shared__ float s_sq[32];
    if (STATS) {
        if (threadIdx.x < 32) { s_sum[threadIdx.x] = 0.f; s_sq[threadIdx.x] = 0.f; }
        __syncthreads();
    }

    const int chunk = blockIdx.x & (NCHUNK - 1);
    const int nblk  = blockIdx.x / NCHUNK;
    const int g     = threadIdx.x >> 2;     // node within block: 0..63
    const int lane  = threadIdx.x & 3;      // uint4 within the 64B row
    const int node  = nblk * 64 + g;

    __half2 acch[4];
#pragma unroll
    for (int c = 0; c < 4; ++c) acch[c] = __half2(__float2half_rn(0.f), __float2half_rn(0.f));
    float o[8];
#pragma unroll
    for (int c = 0; c < 8; ++c) o[c] = 0.f;

    if (node < n) {
        const uint4* Hc = (const uint4*)Hs + (size_t)chunk * n * 4;  // 4 uint4/node

        {   // self row (dis pre-folded into Hs)
            uint4 v = Hc[(size_t)node * 4 + lane];
            ACCPK(v);
        }
        const int beg = row_ptr[node];
        const int end = row_ptr[node + 1];
        int j = beg;
        const int end8 = beg + ((end - beg) & ~7);
        for (; j < end8; j += 8) {
            int s[8];
#pragma unroll
            for (int u = 0; u < 8; ++u) s[u] = esrc[j + u];
            uint4 va[8];
#pragma unroll
            for (int u = 0; u < 8; ++u) va[u] = Hc[(size_t)s[u] * 4 + lane];
#pragma unroll
            for (int u = 0; u < 8; ++u) { ACCPK(va[u]); }
        }
        for (; j < end; ++j) {
            int s = esrc[j];
            uint4 a = Hc[(size_t)s * 4 + lane];
            ACCPK(a);
        }

        float dd = dis[node];
        const float4* B4 = (const float4*)b + chunk * 8 + lane * 2;
        float4 b0 = B4[0];
        float4 b1 = B4[1];
        float2 f0 = __half22float2(acch[0]);
        float2 f1 = __half22float2(acch[1]);
        float2 f2 = __half22float2(acch[2]);
        float2 f3 = __half22float2(acch[3]);
        o[0] = f0.x * dd + b0.x;
        o[1] = f0.y * dd + b0.y;
        o[2] = f1.x * dd + b0.z;
        o[3] = f1.y * dd + b0.w;
        o[4] = f2.x * dd + b1.x;
        o[5] = f2.y * dd + b1.y;
        o[6] = f3.x * dd + b1.z;
        o[7] = f3.y * dd + b1.w;

        if (OUTF16) {
            union { ushort us[8]; uint4 v; } pk;
#pragma unroll
            for (int c = 0; c < 8; ++c) pk.us[c] = f2h(o[c]);
            ((uint4*)Ov)[(size_t)node * (OUTD / 8) + chunk * 4 + lane] = pk.v;
        } else {
            float4* O4 = (float4*)Ov + (size_t)node * (OUTD / 4) + chunk * 8 + lane * 2;
            O4[0] = make_float4(o[0], o[1], o[2], o[3]);
            O4[1] = make_float4(o[4], o[5], o[6], o[7]);
        }
    }

    if (STATS) {
        // 16 lanes of a wave with equal (lane&3) hold the same 8 columns
        float sv[8], qv[8];
#pragma unroll
        for (int c = 0; c < 8; ++c) { sv[c] = o[c]; qv[c] = o[c] * o[c]; }
#pragma unroll
        for (int c = 0; c < 8; ++c) {
#pragma unroll
            for (int m = 4; m <= 32; m <<= 1) {
                sv[c] += __shfl_xor(sv[c], m);
                qv[c] += __shfl_xor(qv[c], m);
            }
        }
        if ((threadIdx.x & 63) < 4) {
            int c0 = lane * 8;
#pragma unroll
            for (int c = 0; c < 8; ++c) {
                atomicAdd(&s_sum[c0 + c], sv[c]);
                atomicAdd(&s_sq[c0 + c], qv[c]);
            }
        }
        __syncthreads();
        if (threadIdx.x < 32) {
            atomicAdd(&sums[chunk * 32 + threadIdx.x], s_sum[threadIdx.x]);
            atomicAdd(&sumsq[chunk * 32 + threadIdx.x], s_sq[threadIdx.x]);
        }
    }
}

// ---------------------------------------------------------------------------
extern "C" void kernel_launch(void* const* d_in, const int* in_sizes, int n_in,
                              void* d_out, int out_size, void* d_ws, size_t ws_size,
                              hipStream_t stream) {
    const float* x   = (const float*)d_in[0];
    const int*   ei  = (const int*)d_in[1];
    const float* W1  = (const float*)d_in[2];
    const float* b1  = (const float*)d_in[3];
    const float* g1  = (const float*)d_in[4];
    const float* be1 = (const float*)d_in[5];
    const float* W2  = (const float*)d_in[6];
    const float* b2  = (const float*)d_in[7];
    const float* g2  = (const float*)d_in[8];
    const float* be2 = (const float*)d_in[9];
    const float* W3  = (const float*)d_in[10];
    const float* b3  = (const float*)d_in[11];
    float* out = (float*)d_out;

    const int N = in_sizes[0] / 128;
    const int E = in_sizes[1] / 2;
    const int* src = ei;
    const int* dst = ei + E;
    const int NBUK = (N + 127) >> BSH;

    // ---- workspace layout ----
    float* wsp   = (float*)d_ws;
    float* dis   = wsp;                               // N f32
    float* stats = wsp + N;                           // 512 f32 (2 banks)
    ushort* wt1  = (ushort*)(stats + 512);            // 128*128 f16
    ushort* wt2  = wt1 + 128 * 128;
    ushort* wt3  = wt2 + 128 * 128;                   // 128*64 f16
    int*   hist   = (int*)(wt3 + 128 * 64);           // NBUK*8
    int*   cur    = hist + NBUK * NXCD;               // NBUK*8
    int*   bstart = cur + NBUK * NXCD;                // NBUK+1
    int*   row_ptr = bstart + NBUK + 1 + 63;          // N+1
    float* bufA  = (float*)((((uintptr_t)(row_ptr + N + 1)) + 255) & ~(uintptr_t)255);
    float* bufB  = bufA + (size_t)N * 128;            // N*128 region (f16 used)
    unsigned int* ebuf = (unsigned int*)(bufB + (size_t)N * 128);  // E u32
    int*   esrc  = (int*)(ebuf + E);                  // E int

    ushort* Hs  = (ushort*)bufA;                      // [NCHUNK][N][32] f16
    ushort* Bf16 = (ushort*)bufB;                     // [N][128] f16 inter-layer

    float* statsA = stats;        // sums|sumsq layer 1
    float* statsB = stats + 256;  // sums|sumsq layer 2

    const int BS = 256;
    dim3 blk(BS);
    const int SGRID = 128;                 // count/scatter blocks (multiple of 8)
    const int EPB = (E + SGRID - 1) / SGRID;

    // ---- bucket-sorted CSR build ----
    hipMemsetAsync(hist, 0, (size_t)NBUK * NXCD * 4, stream);
    countwt_k<<<dim3(SGRID + 3), blk, 0, stream>>>(dst, hist, E, EPB, NBUK,
                                                   W1, W2, W3, wt1, wt2, wt3);
    scan_hist_k<<<dim3(1), blk, 0, stream>>>(hist, cur, bstart, row_ptr, stats, NBUK, N, E);
    scatter_bucket_k<<<dim3(SGRID), blk, 0, stream>>>(src, dst, cur, ebuf, E, EPB, NBUK);
    bucket_sort_k<<<dim3(NBUK), blk, 0, stream>>>(ebuf, bstart, row_ptr, esrc, dis, N);

    const int gemm_grid = (N + 63) / 64;
    const int NBg = (N + 63) / 64;      // gather node-blocks (64 nodes/block)

    // ---- layer 1 ----
    gemm_reg_k<128, false, false><<<dim3(gemm_grid), blk, 0, stream>>>(
        x, wt1, nullptr, nullptr, nullptr, dis, Hs, N);
    gather_k<128, true, true><<<dim3(NBg * 4), blk, 0, stream>>>(
        Hs, dis, b1, row_ptr, esrc, Bf16, statsA, statsA + 128, N);

    // ---- layer 2 (BN computed per-block from statsA inside GEMM) ----
    gemm_reg_k<128, true, true><<<dim3(gemm_grid), blk, 0, stream>>>(
        Bf16, wt2, statsA, g1, be1, dis, Hs, N);
    gather_k<128, true, true><<<dim3(NBg * 4), blk, 0, stream>>>(
        Hs, dis, b2, row_ptr, esrc, Bf16, statsB, statsB + 128, N);

    // ---- layer 3 (OUT = 64, BN from statsB, f32 straight to d_out) ----
    gemm_reg_k<64, true, true><<<dim3(gemm_grid), blk, 0, stream>>>(
        Bf16, wt3, statsB, g2, be2, dis, Hs, N);
    gather_k<64, false, false><<<dim3(NBg * 2), blk, 0, stream>>>(
        Hs, dis, b3, row_ptr, esrc, out, nullptr, nullptr, N);
}